// Round 7
// baseline (209.665 us; speedup 1.0000x reference)
//
#include <hip/hip_runtime.h>
#include <hip/hip_bf16.h>

// Problem constants
#define B_    32
#define T_    512
#define C_    384
#define D_    1536      // C*MULT
#define H_    1024
#define L_    255       // (T-SIZE)/STRIDE + 1
#define KP_   6144      // SIZE*D
#define ND_   16

// 8-wave 256x256 tile, BK=64, wave tile 128x64 (2M x 4N).
// LDS: 2 buffers x (A 32KB + B 32KB) = 128KB.
// Per K64-tile: 2 barriers only (entry, pre-stA). Reads front-loaded,
// MFMA overlaps outstanding reads via counted lgkmcnt. Counted vmcnt(4):
// at tile entry only stA(u+1) may remain in flight.
// Ring: stB(u+1) issued after entry barrier (buf^1 B); stA(u+2) issued
// after mid barrier (all A reads of buf done).
#define TILEB 65536
#define LDS_TOT 131072

using f32x4 = __attribute__((ext_vector_type(4))) float;
using s16x8 = __attribute__((ext_vector_type(8))) short;

__device__ __forceinline__ void gld_lds16(const void* g, void* l) {
    __builtin_amdgcn_global_load_lds(
        (const __attribute__((address_space(1))) void*)g,
        (__attribute__((address_space(3))) void*)l,
        16, 0, 0);
}

__device__ __forceinline__ f32x4 MFMA(s16x8 a, s16x8 b, f32x4 c) {
    return __builtin_amdgcn_mfma_f32_16x16x32_bf16(a, b, c, 0, 0, 0);
}

// ------------- prep: all f32->bf16 conversions + mask/ts, one launch ----
__global__ __launch_bounds__(256) void prep(
    const float* __restrict__ sp, const float* __restrict__ we,
    const float* __restrict__ wp, const int* __restrict__ mIn,
    const int* __restrict__ tIn,
    __hip_bfloat16* __restrict__ spB, __hip_bfloat16* __restrict__ weB,
    __hip_bfloat16* __restrict__ wpB, float* __restrict__ out) {
    int id = blockIdx.x * 256 + threadIdx.x;
    const float* src; __hip_bfloat16* dst; int idx;
    if (id < 1572864)       { src = sp; dst = spB; idx = id; }
    else if (id < 3932160)  { src = we; dst = weB; idx = id - 1572864; }
    else if (id < 5505024)  { src = wp; dst = wpB; idx = id - 3932160; }
    else {
        int i = id - 5505024;
        if (i < B_ * L_) {
            int b = i / L_, l = i % L_;
            const int* mb = mIn + b * T_ + 2 * l;
            int m = mb[0] * mb[1] * mb[2] * mb[3];
            const size_t offM = (size_t)B_ * L_ * H_;
            out[offM + i] = (float)m;
            out[offM + (size_t)B_ * L_ + i] = (float)tIn[b * T_ + l];
        }
        return;
    }
    float4 v = reinterpret_cast<const float4*>(src)[idx];
    __hip_bfloat16 o[4] = {__float2bfloat16(v.x), __float2bfloat16(v.y),
                           __float2bfloat16(v.z), __float2bfloat16(v.w)};
    reinterpret_cast<ushort4*>(dst)[idx] = *reinterpret_cast<ushort4*>(o);
}

// --- one K64 iteration, overlap-structured (2 barriers, counted waits) ---
template <class FB, class FA>
__device__ __forceinline__ void iter_k64(const char* bufA, const char* bufB,
                                         const int (&aB)[8], const int (&bB)[4],
                                         int c0, int c1,
                                         f32x4 (&acc)[8][4], bool last,
                                         FB&& stB, FA&& stA) {
    s16x8 A0[4][2], A1[4][2], B0[2][2], B1[2][2];
    if (last) { asm volatile("s_waitcnt vmcnt(0)" ::: "memory"); }
    else      { asm volatile("s_waitcnt vmcnt(4)" ::: "memory"); }
    __builtin_amdgcn_s_barrier();
    stB();                                    // B(u+1) -> other buffer
    // front-load all A0, B0, A1 reads (20 x ds_read_b128)
    #pragma unroll
    for (int mi = 0; mi < 4; ++mi) {
        A0[mi][0] = *(const s16x8*)(bufA + aB[mi] + c0);
        A0[mi][1] = *(const s16x8*)(bufA + aB[mi] + c1);
    }
    #pragma unroll
    for (int ni = 0; ni < 2; ++ni) {
        B0[ni][0] = *(const s16x8*)(bufB + bB[ni] + c0);
        B0[ni][1] = *(const s16x8*)(bufB + bB[ni] + c1);
    }
    #pragma unroll
    for (int mi = 0; mi < 4; ++mi) {
        A1[mi][0] = *(const s16x8*)(bufA + aB[4 + mi] + c0);
        A1[mi][1] = *(const s16x8*)(bufA + aB[4 + mi] + c1);
    }
    asm volatile("s_waitcnt lgkmcnt(8)" ::: "memory");   // A0,B0 ready
    __builtin_amdgcn_sched_barrier(0);
    __builtin_amdgcn_s_setprio(1);
    #pragma unroll
    for (int mi = 0; mi < 4; ++mi)
        #pragma unroll
        for (int ni = 0; ni < 2; ++ni)
            #pragma unroll
            for (int ks = 0; ks < 2; ++ks)
                acc[mi][ni] = MFMA(A0[mi][ks], B0[ni][ks], acc[mi][ni]);
    __builtin_amdgcn_s_setprio(0);
    asm volatile("s_waitcnt lgkmcnt(0)" ::: "memory");   // A1 ready
    __builtin_amdgcn_sched_barrier(0);
    #pragma unroll
    for (int ni = 0; ni < 2; ++ni) {                     // issue B1 reads
        B1[ni][0] = *(const s16x8*)(bufB + bB[2 + ni] + c0);
        B1[ni][1] = *(const s16x8*)(bufB + bB[2 + ni] + c1);
    }
    __builtin_amdgcn_sched_barrier(0);                   // keep B1 issue early
    __builtin_amdgcn_s_setprio(1);
    #pragma unroll
    for (int mi = 0; mi < 4; ++mi)
        #pragma unroll
        for (int ni = 0; ni < 2; ++ni)
            #pragma unroll
            for (int ks = 0; ks < 2; ++ks)
                acc[4 + mi][ni] = MFMA(A1[mi][ks], B0[ni][ks], acc[4 + mi][ni]);
    __builtin_amdgcn_s_setprio(0);
    __builtin_amdgcn_s_barrier();                        // all A reads done
    stA();                                    // A(u+2) -> this buffer's A
    asm volatile("s_waitcnt lgkmcnt(0)" ::: "memory");   // B1 ready
    __builtin_amdgcn_sched_barrier(0);
    __builtin_amdgcn_s_setprio(1);
    #pragma unroll
    for (int mi = 0; mi < 4; ++mi)
        #pragma unroll
        for (int ni = 0; ni < 2; ++ni)
            #pragma unroll
            for (int ks = 0; ks < 2; ++ks)
                acc[mi][2 + ni] = MFMA(A0[mi][ks], B1[ni][ks], acc[mi][2 + ni]);
    #pragma unroll
    for (int mi = 0; mi < 4; ++mi)
        #pragma unroll
        for (int ni = 0; ni < 2; ++ni)
            #pragma unroll
            for (int ks = 0; ks < 2; ++ks)
                acc[4 + mi][2 + ni] = MFMA(A1[mi][ks], B1[ni][ks], acc[4 + mi][2 + ni]);
    __builtin_amdgcn_s_setprio(0);
    // no closing barrier: next tile's vmcnt+barrier covers it
}

// ---------------- GEMM1: x1 = gelu(spikes @ Wg^T + bg) * 32, bf16 out ----
// grid 384 1-D XCD-swizzled; BM=256(t) BN=256(d), KT2 = 6 K64-tiles.
__global__ __launch_bounds__(512, 2) void gemm1_embed(
    const __hip_bfloat16* __restrict__ Sp,
    const __hip_bfloat16* __restrict__ We,
    const float* __restrict__ bEmb,
    const int* __restrict__ dateIdx,
    __hip_bfloat16* __restrict__ X1) {
    extern __shared__ __align__(16) char lds[];
    const int tid  = threadIdx.x;
    const int lane = tid & 63, wid = tid >> 6;
    const int wm = wid >> 2, wn = wid & 3;
    const int id   = blockIdx.x;              // 0..383
    const int xcd  = id & 7, slot = id >> 3;  // slot 0..47
    const int b    = xcd * 4 + slot / 12;
    const int tile = slot % 12;
    const int m0   = (tile & 1) * 256;
    const int n0   = (tile >> 1) * 256;
    const int didx = dateIdx[b];
    const __hip_bfloat16* Ab = Sp + (size_t)b * T_ * C_;
    const __hip_bfloat16* Bm = We + (size_t)didx * D_ * C_;
    const int KT2 = C_ / 64;                  // 6

    const __hip_bfloat16* aP[4]; const __hip_bfloat16* bP[4]; int sD[4];
    #pragma unroll
    for (int i = 0; i < 4; ++i) {
        int p = i * 512 + tid;
        int row = p >> 3;
        int cl  = (p & 7) ^ (row & 7);
        aP[i] = Ab + (size_t)(m0 + row) * C_ + cl * 8;
        bP[i] = Bm + (size_t)(n0 + row) * C_ + cl * 8;
        sD[i] = (i * 512 + wid * 64) * 16;
    }
    auto stAf = [&](int kt, char* dst) {
        int ko = kt * 64;
        #pragma unroll
        for (int i = 0; i < 4; ++i) gld_lds16(aP[i] + ko, dst + sD[i]);
    };
    auto stBf = [&](int kt, char* dst) {
        int ko = kt * 64;
        #pragma unroll
        for (int i = 0; i < 4; ++i) gld_lds16(bP[i] + ko, dst + sD[i]);
    };

    const int rl = lane & 15, g = lane >> 4;
    const int c0 = ((g ^ (rl & 7)) << 4), c1 = (((4 + g) ^ (rl & 7)) << 4);
    int aB[8], bB[4];
    #pragma unroll
    for (int mi = 0; mi < 8; ++mi) aB[mi] = (wm * 128 + mi * 16 + rl) * 128;
    #pragma unroll
    for (int ni = 0; ni < 4; ++ni) bB[ni] = (wn * 64 + ni * 16 + rl) * 128;

    f32x4 acc[8][4] = {};
    stAf(0, lds);
    stBf(0, lds + 32768);
    stAf(1, lds + TILEB);
    for (int u = 0; u < KT2; ++u) {
        const char* bA = lds + (u & 1) * TILEB;
        iter_k64(bA, bA + 32768, aB, bB, c0, c1, acc, u == KT2 - 1,
                 [&]{ if (u + 1 < KT2) stBf(u + 1, lds + ((u + 1) & 1) * TILEB + 32768); },
                 [&]{ if (u + 2 < KT2) stAf(u + 2, lds + (u & 1) * TILEB); });
    }

    // epilogue: + bias, exact gelu, * 32, store bf16
    #pragma unroll
    for (int mi = 0; mi < 8; ++mi) {
        #pragma unroll
        for (int ni = 0; ni < 4; ++ni) {
            int col = n0 + wn * 64 + ni * 16 + rl;               // d
            float bg = bEmb[didx * D_ + col];
            #pragma unroll
            for (int r = 0; r < 4; ++r) {
                int row = m0 + wm * 128 + mi * 16 + g * 4 + r;   // t
                float v = acc[mi][ni][r] + bg;
                float gl = 0.5f * v * (1.0f + erff(v * 0.70710678118f)) * 32.0f;
                X1[((size_t)b * T_ + row) * D_ + col] = __float2bfloat16(gl);
            }
        }
    }
}

// ---------------- GEMM2 split-K x2: partial = patches(dslice) @ Wp^T -----
// grid 256 1-D XCD batch-major; BM=256(l) BN=256(h), 48 K64-tiles per half.
__global__ __launch_bounds__(512, 2) void gemm2_proj(
    const __hip_bfloat16* __restrict__ X1,
    const __hip_bfloat16* __restrict__ Wp,
    float* __restrict__ outX,                  // partial kh=0
    __hip_bfloat16* __restrict__ P1) {         // partial kh=1
    extern __shared__ __align__(16) char lds[];
    const int tid  = threadIdx.x;
    const int lane = tid & 63, wid = tid >> 6;
    const int wm = wid >> 2, wn = wid & 3;
    const int id   = blockIdx.x;               // 0..255
    const int xcd  = id & 7, slot = id >> 3;   // 0..31
    const int b    = xcd * 4 + (slot >> 3);
    const int sub  = slot & 7;
    const int kh   = sub >> 2;
    const int n0   = (sub & 3) * 256;
    const __hip_bfloat16* Xb = X1 + (size_t)b * T_ * D_;
    const int KT2 = 48;

    const __hip_bfloat16* aP[4]; const __hip_bfloat16* bP[4]; int sD[4];
    #pragma unroll
    for (int i = 0; i < 4; ++i) {
        int p = i * 512 + tid;
        int row = p >> 3;
        int cl  = (p & 7) ^ (row & 7);
        int l = row < 255 ? row : 254;
        aP[i] = Xb + (size_t)(2 * l) * D_ + cl * 8;
        bP[i] = Wp + (size_t)(n0 + row) * KP_ + cl * 8;
        sD[i] = (i * 512 + wid * 64) * 16;
    }
    auto kofs = [&](int kt) { return (kt & 3) * D_ + kh * 768 + (kt >> 2) * 64; };
    auto stAf = [&](int kt, char* dst) {
        int ko = kofs(kt);
        #pragma unroll
        for (int i = 0; i < 4; ++i) gld_lds16(aP[i] + ko, dst + sD[i]);
    };
    auto stBf = [&](int kt, char* dst) {
        int ko = kofs(kt);
        #pragma unroll
        for (int i = 0; i < 4; ++i) gld_lds16(bP[i] + ko, dst + sD[i]);
    };

    const int rl = lane & 15, g = lane >> 4;
    const int c0 = ((g ^ (rl & 7)) << 4), c1 = (((4 + g) ^ (rl & 7)) << 4);
    int aB[8], bB[4];
    #pragma unroll
    for (int mi = 0; mi < 8; ++mi) aB[mi] = (wm * 128 + mi * 16 + rl) * 128;
    #pragma unroll
    for (int ni = 0; ni < 4; ++ni) bB[ni] = (wn * 64 + ni * 16 + rl) * 128;

    f32x4 acc[8][4] = {};
    stAf(0, lds);
    stBf(0, lds + 32768);
    stAf(1, lds + TILEB);
    for (int u = 0; u < KT2; ++u) {
        const char* bA = lds + (u & 1) * TILEB;
        iter_k64(bA, bA + 32768, aB, bB, c0, c1, acc, u == KT2 - 1,
                 [&]{ if (u + 1 < KT2) stBf(u + 1, lds + ((u + 1) & 1) * TILEB + 32768); },
                 [&]{ if (u + 2 < KT2) stAf(u + 2, lds + (u & 1) * TILEB); });
    }

    // epilogue: raw partial store (bias/pos added in combine)
    #pragma unroll
    for (int mi = 0; mi < 8; ++mi) {
        #pragma unroll
        for (int ni = 0; ni < 4; ++ni) {
            int h = n0 + wn * 64 + ni * 16 + rl;
            #pragma unroll
            for (int r = 0; r < 4; ++r) {
                int l = wm * 128 + mi * 16 + g * 4 + r;
                if (l < L_) {
                    size_t o = ((size_t)b * L_ + l) * H_ + h;
                    if (kh == 0) outX[o] = acc[mi][ni][r];
                    else         P1[o]  = __float2bfloat16(acc[mi][ni][r]);
                }
            }
        }
    }
}

// ---------------- combine: out = p0(out) + p1 + b_proj + pos_table[ts] ----
__global__ __launch_bounds__(256) void combine(
    const __hip_bfloat16* __restrict__ P1,
    const float* __restrict__ bProj,
    const float* __restrict__ posTab,
    const int* __restrict__ tsIn,
    float* __restrict__ outX) {
    const int l = blockIdx.x, b = blockIdx.y;
    const int h = threadIdx.x * 4;
    const size_t o4 = ((size_t)(b * L_ + l) * H_ + h) >> 2;
    const int tsv = tsIn[b * T_ + l];
    float4 v = reinterpret_cast<float4*>(outX)[o4];
    ushort4 u = reinterpret_cast<const ushort4*>(P1)[o4];
    union { unsigned ui; float f; } c0, c1, c2, c3;
    c0.ui = (unsigned)u.x << 16; c1.ui = (unsigned)u.y << 16;
    c2.ui = (unsigned)u.z << 16; c3.ui = (unsigned)u.w << 16;
    float4 bp = reinterpret_cast<const float4*>(bProj)[h >> 2];
    float4 pt = reinterpret_cast<const float4*>(posTab + (size_t)tsv * H_)[h >> 2];
    v.x += c0.f + bp.x + pt.x;
    v.y += c1.f + bp.y + pt.y;
    v.z += c2.f + bp.z + pt.z;
    v.w += c3.f + bp.w + pt.w;
    reinterpret_cast<float4*>(outX)[o4] = v;
}

extern "C" void kernel_launch(void* const* d_in, const int* in_sizes, int n_in,
                              void* d_out, int out_size, void* d_ws, size_t ws_size,
                              hipStream_t stream) {
    (void)in_sizes; (void)n_in; (void)out_size; (void)ws_size;
    const float* spikes  = (const float*)d_in[0];
    const int*   smask   = (const int*)d_in[1];
    const int*   sts     = (const int*)d_in[2];
    const int*   dateIdx = (const int*)d_in[3];
    const float* Wemb    = (const float*)d_in[4];
    const float* bEmb    = (const float*)d_in[5];
    const float* Wproj   = (const float*)d_in[6];
    const float* bProj   = (const float*)d_in[7];
    const float* posTab  = (const float*)d_in[8];
    float* out = (float*)d_out;

    // workspace layout (bytes):
    // X1 bf16   [B][T][D]  : 50331648                 @ 0
    // SpB bf16  [B][T][C]  : 12582912                 @ 50331648
    // WeB bf16  [ND][D][C] : 18874368                 @ 62914560  (dead after gemm1)
    //   P1 bf16 [B][L][H]  : 16711680                 @ 62914560  (aliases WeB)
    // WpB bf16  [H][KP]    : 12582912                 @ 81788928
    char* ws = (char*)d_ws;
    __hip_bfloat16* X1  = (__hip_bfloat16*)(ws);
    __hip_bfloat16* SpB = (__hip_bfloat16*)(ws + 50331648);
    __hip_bfloat16* WeB = (__hip_bfloat16*)(ws + 62914560);
    __hip_bfloat16* P1  = (__hip_bfloat16*)(ws + 62914560);
    __hip_bfloat16* WpB = (__hip_bfloat16*)(ws + 81788928);

    hipFuncSetAttribute((const void*)gemm1_embed,
                        hipFuncAttributeMaxDynamicSharedMemorySize, LDS_TOT);
    hipFuncSetAttribute((const void*)gemm2_proj,
                        hipFuncAttributeMaxDynamicSharedMemorySize, LDS_TOT);

    prep<<<21536, 256, 0, stream>>>(spikes, Wemb, Wproj, smask, sts,
                                    SpB, WeB, WpB, out);

    gemm1_embed<<<384, 512, LDS_TOT, stream>>>(SpB, WeB, bEmb, dateIdx, X1);

    gemm2_proj<<<256, 512, LDS_TOT, stream>>>(X1, WpB, out, P1);

    dim3 gc(L_, B_);
    combine<<<gc, 256, 0, stream>>>(P1, bProj, posTab, sts, out);
}

// Round 8
// 193.507 us; speedup vs baseline: 1.0835x; 1.0835x over previous
//
#include <hip/hip_runtime.h>
#include <hip/hip_bf16.h>

// Problem constants
#define B_    32
#define T_    512
#define C_    384
#define D_    1536      // C*MULT
#define H_    1024
#define L_    255       // (T-SIZE)/STRIDE + 1
#define KP_   6144      // SIZE*D
#define ND_   16

// gemm1 (light): BM=256 BN=128 BK=32, 4 waves, wave tile 128x64, tri-buffer
//   vmcnt(12) pipeline, 3 x 24KB LDS -> 2 blocks/CU.  (r4-proven, ~11us)
// gemm2 (heavy): 8-wave 256x256, BK=64, 2x64KB LDS, 2-barrier overlap
//   iter (r7), split-K x2 + combine.
#define BUF1 24576
#define TILEB 65536
#define LDS_TOT 131072

using f32x4 = __attribute__((ext_vector_type(4))) float;
using s16x8 = __attribute__((ext_vector_type(8))) short;

__device__ __forceinline__ void gld_lds16(const void* g, void* l) {
    __builtin_amdgcn_global_load_lds(
        (const __attribute__((address_space(1))) void*)g,
        (__attribute__((address_space(3))) void*)l,
        16, 0, 0);
}

__device__ __forceinline__ f32x4 MFMA(s16x8 a, s16x8 b, f32x4 c) {
    return __builtin_amdgcn_mfma_f32_16x16x32_bf16(a, b, c, 0, 0, 0);
}

// ------------- prep: all f32->bf16 conversions + mask/ts, one launch ----
__global__ __launch_bounds__(256) void prep(
    const float* __restrict__ sp, const float* __restrict__ we,
    const float* __restrict__ wp, const int* __restrict__ mIn,
    const int* __restrict__ tIn,
    __hip_bfloat16* __restrict__ spB, __hip_bfloat16* __restrict__ weB,
    __hip_bfloat16* __restrict__ wpB, float* __restrict__ out) {
    int id = blockIdx.x * 256 + threadIdx.x;
    const float* src; __hip_bfloat16* dst; int idx;
    if (id < 1572864)       { src = sp; dst = spB; idx = id; }
    else if (id < 3932160)  { src = we; dst = weB; idx = id - 1572864; }
    else if (id < 5505024)  { src = wp; dst = wpB; idx = id - 3932160; }
    else {
        int i = id - 5505024;
        if (i < B_ * L_) {
            int b = i / L_, l = i % L_;
            const int* mb = mIn + b * T_ + 2 * l;
            int m = mb[0] * mb[1] * mb[2] * mb[3];
            const size_t offM = (size_t)B_ * L_ * H_;
            out[offM + i] = (float)m;
            out[offM + (size_t)B_ * L_ + i] = (float)tIn[b * T_ + l];
        }
        return;
    }
    float4 v = reinterpret_cast<const float4*>(src)[idx];
    __hip_bfloat16 o[4] = {__float2bfloat16(v.x), __float2bfloat16(v.y),
                           __float2bfloat16(v.z), __float2bfloat16(v.w)};
    reinterpret_cast<ushort4*>(dst)[idx] = *reinterpret_cast<ushort4*>(o);
}

// ======================= gemm1 engine (r4, light) ========================
// One K=32 tile for a 128x64 wave tile: 8 A-frags, 4 B-frags, 32 MFMA in 4
// phases of 8; B[q+1] read issued under phase-q MFMAs; counted lgkm waits.
__device__ __forceinline__ void ktile32(const char* la, const char* lb,
                                        const int* aOff, const int* bOff,
                                        f32x4 (&acc)[8][4]) {
    s16x8 A[8], Bv[4];
    #pragma unroll
    for (int i = 0; i < 8; ++i) A[i] = *(const s16x8*)(la + aOff[i]);
    Bv[0] = *(const s16x8*)(lb + bOff[0]);
    Bv[1] = *(const s16x8*)(lb + bOff[1]);
    asm volatile("s_waitcnt lgkmcnt(1)" ::: "memory");
    __builtin_amdgcn_sched_barrier(0);
    __builtin_amdgcn_s_setprio(1);
    #pragma unroll
    for (int mi = 0; mi < 8; ++mi)
        acc[mi][0] = MFMA(A[mi], Bv[0], acc[mi][0]);
    __builtin_amdgcn_s_setprio(0);
    Bv[2] = *(const s16x8*)(lb + bOff[2]);
    asm volatile("s_waitcnt lgkmcnt(1)" ::: "memory");
    __builtin_amdgcn_sched_barrier(0);
    __builtin_amdgcn_s_setprio(1);
    #pragma unroll
    for (int mi = 0; mi < 8; ++mi)
        acc[mi][1] = MFMA(A[mi], Bv[1], acc[mi][1]);
    __builtin_amdgcn_s_setprio(0);
    Bv[3] = *(const s16x8*)(lb + bOff[3]);
    asm volatile("s_waitcnt lgkmcnt(1)" ::: "memory");
    __builtin_amdgcn_sched_barrier(0);
    __builtin_amdgcn_s_setprio(1);
    #pragma unroll
    for (int mi = 0; mi < 8; ++mi)
        acc[mi][2] = MFMA(A[mi], Bv[2], acc[mi][2]);
    __builtin_amdgcn_s_setprio(0);
    asm volatile("s_waitcnt lgkmcnt(0)" ::: "memory");
    __builtin_amdgcn_sched_barrier(0);
    __builtin_amdgcn_s_setprio(1);
    #pragma unroll
    for (int mi = 0; mi < 8; ++mi)
        acc[mi][3] = MFMA(A[mi], Bv[3], acc[mi][3]);
    __builtin_amdgcn_s_setprio(0);
}

// ---------------- GEMM1: x1 = gelu(spikes @ Wg^T + bg) * 32, bf16 out ----
// grid 768 1-D, XCD batch-major. 256 threads, 4 waves 2Mx2N, wave tile 128x64.
__global__ __launch_bounds__(256, 2) void gemm1_embed(
    const __hip_bfloat16* __restrict__ Sp,
    const __hip_bfloat16* __restrict__ We,
    const float* __restrict__ bEmb,
    const int* __restrict__ dateIdx,
    __hip_bfloat16* __restrict__ X1) {
    extern __shared__ __align__(16) char lds[];
    const int tid  = threadIdx.x;
    const int lane = tid & 63, wid = tid >> 6;
    const int wm = wid >> 1, wn = wid & 1;
    const int id   = blockIdx.x;             // 0..767
    const int xcd  = id & 7, slot = id >> 3; // slot 0..95
    const int b    = xcd * 4 + slot / 24;
    const int tile = slot % 24;
    const int m0   = (tile & 1) * 256;
    const int n0   = (tile >> 1) * 128;
    const int didx = dateIdx[b];
    const __hip_bfloat16* A  = Sp + (size_t)b * T_ * C_;
    const __hip_bfloat16* Bm = We + (size_t)didx * D_ * C_;
    const int KT = C_ / 32;                   // 12

    const __hip_bfloat16* aSrc[4]; const __hip_bfloat16* bSrc[2];
    int aDst[4], bDst[2];
    #pragma unroll
    for (int i = 0; i < 4; ++i) {
        int p = i * 256 + tid;                // 0..1023
        int row = p >> 2;
        int cl  = (p & 3) ^ ((row >> 1) & 3);
        aSrc[i] = A + (size_t)(m0 + row) * C_ + cl * 8;
        aDst[i] = (i * 256 + wid * 64) * 16;
    }
    #pragma unroll
    for (int i = 0; i < 2; ++i) {
        int p = i * 256 + tid;                // 0..511
        int row = p >> 2;
        int cl  = (p & 3) ^ ((row >> 1) & 3);
        bSrc[i] = Bm + (size_t)(n0 + row) * C_ + cl * 8;
        bDst[i] = 16384 + (i * 256 + wid * 64) * 16;
    }

    auto stage = [&](int kt, int buf) {
        char* lb0 = lds + buf * BUF1;
        int ko = kt * 32;
        #pragma unroll
        for (int i = 0; i < 4; ++i) gld_lds16(aSrc[i] + ko, lb0 + aDst[i]);
        #pragma unroll
        for (int i = 0; i < 2; ++i) gld_lds16(bSrc[i] + ko, lb0 + bDst[i]);
    };

    const int rl = lane & 15, g = lane >> 4;
    int aOff[8], bOff[4];
    #pragma unroll
    for (int mi = 0; mi < 8; ++mi) {
        int r = wm * 128 + mi * 16 + rl;
        aOff[mi] = r * 64 + (((g ^ (r >> 1)) & 3) << 4) + ((g & ~3) << 4);
    }
    #pragma unroll
    for (int ni = 0; ni < 4; ++ni) {
        int r = wn * 64 + ni * 16 + rl;
        bOff[ni] = 16384 + r * 64 + (((g ^ (r >> 1)) & 3) << 4) + ((g & ~3) << 4);
    }

    f32x4 acc[8][4] = {};
    stage(0, 0);
    stage(1, 1);
    for (int kt = 0; kt < KT - 2; ++kt) {
        stage(kt + 2, (kt + 2) % 3);
        asm volatile("s_waitcnt vmcnt(12)" ::: "memory");
        __builtin_amdgcn_s_barrier();
        const char* la = lds + (kt % 3) * BUF1;
        ktile32(la, la, aOff, bOff, acc);
        __builtin_amdgcn_s_barrier();
    }
    asm volatile("s_waitcnt vmcnt(6)" ::: "memory");
    __builtin_amdgcn_s_barrier();
    ktile32(lds + ((KT - 2) % 3) * BUF1, lds + ((KT - 2) % 3) * BUF1, aOff, bOff, acc);
    asm volatile("s_waitcnt vmcnt(0)" ::: "memory");
    __builtin_amdgcn_s_barrier();
    ktile32(lds + ((KT - 1) % 3) * BUF1, lds + ((KT - 1) % 3) * BUF1, aOff, bOff, acc);

    // epilogue: + bias, exact gelu, * 32, store bf16
    #pragma unroll
    for (int mi = 0; mi < 8; ++mi) {
        #pragma unroll
        for (int ni = 0; ni < 4; ++ni) {
            int col = n0 + wn * 64 + ni * 16 + rl;              // d
            float bg = bEmb[didx * D_ + col];
            #pragma unroll
            for (int r = 0; r < 4; ++r) {
                int row = m0 + wm * 128 + mi * 16 + g * 4 + r;  // t
                float v = acc[mi][ni][r] + bg;
                float gl = 0.5f * v * (1.0f + erff(v * 0.70710678118f)) * 32.0f;
                X1[((size_t)b * T_ + row) * D_ + col] = __float2bfloat16(gl);
            }
        }
    }
}

// ======================= gemm2 engine (r7, heavy) ========================
// one K64 iteration, overlap-structured (2 barriers, counted waits)
template <class FB, class FA>
__device__ __forceinline__ void iter_k64(const char* bufA, const char* bufB,
                                         const int (&aB)[8], const int (&bB)[4],
                                         int c0, int c1,
                                         f32x4 (&acc)[8][4], bool last,
                                         FB&& stB, FA&& stA) {
    s16x8 A0[4][2], A1[4][2], B0[2][2], B1[2][2];
    if (last) { asm volatile("s_waitcnt vmcnt(0)" ::: "memory"); }
    else      { asm volatile("s_waitcnt vmcnt(4)" ::: "memory"); }
    __builtin_amdgcn_s_barrier();
    stB();                                    // B(u+1) -> other buffer
    #pragma unroll
    for (int mi = 0; mi < 4; ++mi) {
        A0[mi][0] = *(const s16x8*)(bufA + aB[mi] + c0);
        A0[mi][1] = *(const s16x8*)(bufA + aB[mi] + c1);
    }
    #pragma unroll
    for (int ni = 0; ni < 2; ++ni) {
        B0[ni][0] = *(const s16x8*)(bufB + bB[ni] + c0);
        B0[ni][1] = *(const s16x8*)(bufB + bB[ni] + c1);
    }
    #pragma unroll
    for (int mi = 0; mi < 4; ++mi) {
        A1[mi][0] = *(const s16x8*)(bufA + aB[4 + mi] + c0);
        A1[mi][1] = *(const s16x8*)(bufA + aB[4 + mi] + c1);
    }
    asm volatile("s_waitcnt lgkmcnt(8)" ::: "memory");   // A0,B0 ready
    __builtin_amdgcn_sched_barrier(0);
    __builtin_amdgcn_s_setprio(1);
    #pragma unroll
    for (int mi = 0; mi < 4; ++mi)
        #pragma unroll
        for (int ni = 0; ni < 2; ++ni)
            #pragma unroll
            for (int ks = 0; ks < 2; ++ks)
                acc[mi][ni] = MFMA(A0[mi][ks], B0[ni][ks], acc[mi][ni]);
    __builtin_amdgcn_s_setprio(0);
    asm volatile("s_waitcnt lgkmcnt(0)" ::: "memory");   // A1 ready
    __builtin_amdgcn_sched_barrier(0);
    #pragma unroll
    for (int ni = 0; ni < 2; ++ni) {                     // issue B1 reads
        B1[ni][0] = *(const s16x8*)(bufB + bB[2 + ni] + c0);
        B1[ni][1] = *(const s16x8*)(bufB + bB[2 + ni] + c1);
    }
    __builtin_amdgcn_sched_barrier(0);                   // keep B1 issue early
    __builtin_amdgcn_s_setprio(1);
    #pragma unroll
    for (int mi = 0; mi < 4; ++mi)
        #pragma unroll
        for (int ni = 0; ni < 2; ++ni)
            #pragma unroll
            for (int ks = 0; ks < 2; ++ks)
                acc[4 + mi][ni] = MFMA(A1[mi][ks], B0[ni][ks], acc[4 + mi][ni]);
    __builtin_amdgcn_s_setprio(0);
    __builtin_amdgcn_s_barrier();                        // all A reads done
    stA();                                    // A(u+2) -> this buffer's A
    asm volatile("s_waitcnt lgkmcnt(0)" ::: "memory");   // B1 ready
    __builtin_amdgcn_sched_barrier(0);
    __builtin_amdgcn_s_setprio(1);
    #pragma unroll
    for (int mi = 0; mi < 4; ++mi)
        #pragma unroll
        for (int ni = 0; ni < 2; ++ni)
            #pragma unroll
            for (int ks = 0; ks < 2; ++ks)
                acc[mi][2 + ni] = MFMA(A0[mi][ks], B1[ni][ks], acc[mi][2 + ni]);
    #pragma unroll
    for (int mi = 0; mi < 4; ++mi)
        #pragma unroll
        for (int ni = 0; ni < 2; ++ni)
            #pragma unroll
            for (int ks = 0; ks < 2; ++ks)
                acc[4 + mi][2 + ni] = MFMA(A1[mi][ks], B1[ni][ks], acc[4 + mi][2 + ni]);
    __builtin_amdgcn_s_setprio(0);
    // no closing barrier: next tile's vmcnt+barrier covers it
}

// ---------------- GEMM2 split-K x2: partial = patches(dslice) @ Wp^T -----
// grid 256 1-D XCD batch-major; BM=256(l) BN=256(h), 48 K64-tiles per half.
__global__ __launch_bounds__(512, 2) void gemm2_proj(
    const __hip_bfloat16* __restrict__ X1,
    const __hip_bfloat16* __restrict__ Wp,
    float* __restrict__ outX,                  // partial kh=0
    __hip_bfloat16* __restrict__ P1) {         // partial kh=1
    extern __shared__ __align__(16) char lds[];
    const int tid  = threadIdx.x;
    const int lane = tid & 63, wid = tid >> 6;
    const int wm = wid >> 2, wn = wid & 3;
    const int id   = blockIdx.x;               // 0..255
    const int xcd  = id & 7, slot = id >> 3;   // 0..31
    const int b    = xcd * 4 + (slot >> 3);
    const int sub  = slot & 7;
    const int kh   = sub >> 2;
    const int n0   = (sub & 3) * 256;
    const __hip_bfloat16* Xb = X1 + (size_t)b * T_ * D_;
    const int KT2 = 48;

    const __hip_bfloat16* aP[4]; const __hip_bfloat16* bP[4]; int sD[4];
    #pragma unroll
    for (int i = 0; i < 4; ++i) {
        int p = i * 512 + tid;
        int row = p >> 3;
        int cl  = (p & 7) ^ (row & 7);
        int l = row < 255 ? row : 254;
        aP[i] = Xb + (size_t)(2 * l) * D_ + cl * 8;
        bP[i] = Wp + (size_t)(n0 + row) * KP_ + cl * 8;
        sD[i] = (i * 512 + wid * 64) * 16;
    }
    auto kofs = [&](int kt) { return (kt & 3) * D_ + kh * 768 + (kt >> 2) * 64; };
    auto stAf = [&](int kt, char* dst) {
        int ko = kofs(kt);
        #pragma unroll
        for (int i = 0; i < 4; ++i) gld_lds16(aP[i] + ko, dst + sD[i]);
    };
    auto stBf = [&](int kt, char* dst) {
        int ko = kofs(kt);
        #pragma unroll
        for (int i = 0; i < 4; ++i) gld_lds16(bP[i] + ko, dst + sD[i]);
    };

    const int rl = lane & 15, g = lane >> 4;
    const int c0 = ((g ^ (rl & 7)) << 4), c1 = (((4 + g) ^ (rl & 7)) << 4);
    int aB[8], bB[4];
    #pragma unroll
    for (int mi = 0; mi < 8; ++mi) aB[mi] = (wm * 128 + mi * 16 + rl) * 128;
    #pragma unroll
    for (int ni = 0; ni < 4; ++ni) bB[ni] = (wn * 64 + ni * 16 + rl) * 128;

    f32x4 acc[8][4] = {};
    stAf(0, lds);
    stBf(0, lds + 32768);
    stAf(1, lds + TILEB);
    for (int u = 0; u < KT2; ++u) {
        const char* bA = lds + (u & 1) * TILEB;
        iter_k64(bA, bA + 32768, aB, bB, c0, c1, acc, u == KT2 - 1,
                 [&]{ if (u + 1 < KT2) stBf(u + 1, lds + ((u + 1) & 1) * TILEB + 32768); },
                 [&]{ if (u + 2 < KT2) stAf(u + 2, lds + (u & 1) * TILEB); });
    }

    // epilogue: raw partial store (bias/pos added in combine)
    #pragma unroll
    for (int mi = 0; mi < 8; ++mi) {
        #pragma unroll
        for (int ni = 0; ni < 4; ++ni) {
            int h = n0 + wn * 64 + ni * 16 + rl;
            #pragma unroll
            for (int r = 0; r < 4; ++r) {
                int l = wm * 128 + mi * 16 + g * 4 + r;
                if (l < L_) {
                    size_t o = ((size_t)b * L_ + l) * H_ + h;
                    if (kh == 0) outX[o] = acc[mi][ni][r];
                    else         P1[o]  = __float2bfloat16(acc[mi][ni][r]);
                }
            }
        }
    }
}

// ---------------- combine: out = p0(out) + p1 + b_proj + pos_table[ts] ----
__global__ __launch_bounds__(256) void combine(
    const __hip_bfloat16* __restrict__ P1,
    const float* __restrict__ bProj,
    const float* __restrict__ posTab,
    const int* __restrict__ tsIn,
    float* __restrict__ outX) {
    const int l = blockIdx.x, b = blockIdx.y;
    const int h = threadIdx.x * 4;
    const size_t o4 = ((size_t)(b * L_ + l) * H_ + h) >> 2;
    const int tsv = tsIn[b * T_ + l];
    float4 v = reinterpret_cast<float4*>(outX)[o4];
    ushort4 u = reinterpret_cast<const ushort4*>(P1)[o4];
    union { unsigned ui; float f; } c0, c1, c2, c3;
    c0.ui = (unsigned)u.x << 16; c1.ui = (unsigned)u.y << 16;
    c2.ui = (unsigned)u.z << 16; c3.ui = (unsigned)u.w << 16;
    float4 bp = reinterpret_cast<const float4*>(bProj)[h >> 2];
    float4 pt = reinterpret_cast<const float4*>(posTab + (size_t)tsv * H_)[h >> 2];
    v.x += c0.f + bp.x + pt.x;
    v.y += c1.f + bp.y + pt.y;
    v.z += c2.f + bp.z + pt.z;
    v.w += c3.f + bp.w + pt.w;
    reinterpret_cast<float4*>(outX)[o4] = v;
}

extern "C" void kernel_launch(void* const* d_in, const int* in_sizes, int n_in,
                              void* d_out, int out_size, void* d_ws, size_t ws_size,
                              hipStream_t stream) {
    (void)in_sizes; (void)n_in; (void)out_size; (void)ws_size;
    const float* spikes  = (const float*)d_in[0];
    const int*   smask   = (const int*)d_in[1];
    const int*   sts     = (const int*)d_in[2];
    const int*   dateIdx = (const int*)d_in[3];
    const float* Wemb    = (const float*)d_in[4];
    const float* bEmb    = (const float*)d_in[5];
    const float* Wproj   = (const float*)d_in[6];
    const float* bProj   = (const float*)d_in[7];
    const float* posTab  = (const float*)d_in[8];
    float* out = (float*)d_out;

    // workspace layout (bytes):
    // X1 bf16   [B][T][D]  : 50331648                 @ 0
    // SpB bf16  [B][T][C]  : 12582912                 @ 50331648
    // WeB bf16  [ND][D][C] : 18874368                 @ 62914560  (dead after gemm1)
    //   P1 bf16 [B][L][H]  : 16711680                 @ 62914560  (aliases WeB)
    // WpB bf16  [H][KP]    : 12582912                 @ 81788928
    char* ws = (char*)d_ws;
    __hip_bfloat16* X1  = (__hip_bfloat16*)(ws);
    __hip_bfloat16* SpB = (__hip_bfloat16*)(ws + 50331648);
    __hip_bfloat16* WeB = (__hip_bfloat16*)(ws + 62914560);
    __hip_bfloat16* P1  = (__hip_bfloat16*)(ws + 62914560);
    __hip_bfloat16* WpB = (__hip_bfloat16*)(ws + 81788928);

    hipFuncSetAttribute((const void*)gemm1_embed,
                        hipFuncAttributeMaxDynamicSharedMemorySize, 3 * BUF1);
    hipFuncSetAttribute((const void*)gemm2_proj,
                        hipFuncAttributeMaxDynamicSharedMemorySize, LDS_TOT);

    prep<<<21536, 256, 0, stream>>>(spikes, Wemb, Wproj, smask, sts,
                                    SpB, WeB, WpB, out);

    gemm1_embed<<<768, 256, 3 * BUF1, stream>>>(SpB, WeB, bEmb, dateIdx, X1);

    gemm2_proj<<<256, 512, LDS_TOT, stream>>>(X1, WpB, out, P1);

    dim3 gc(L_, B_);
    combine<<<gc, 256, 0, stream>>>(P1, bProj, posTab, sts, out);
}

// Round 9
// 167.881 us; speedup vs baseline: 1.2489x; 1.1526x over previous
//
#include <hip/hip_runtime.h>
#include <hip/hip_bf16.h>

// Problem constants
#define B_    32
#define T_    512
#define C_    384
#define D_    1536      // C*MULT
#define H_    1024
#define L_    255       // (T-SIZE)/STRIDE + 1
#define KP_   6144      // SIZE*D
#define ND_   16

// gemm1: r3 engine (188us-config): BM=256 BN=128 BK=64, 8 waves (4Mx2N),
//   tri-buffer 3x48KB, counted vmcnt(12). Grid 768 XCD batch-major.
// gemm2: m201-style 8-barrier schedule: BM=256(l) BN=256(h) BK=64, 8 waves
//   (2Mx4N), wave tile 128x64. LDS 2 x 64KB, K-half-major layout
//   (A h0|A h1|B h0|B h1 = 4 x 16KB). 4 phases/K64 = (ks,nh) quadrants,
//   each {reads; stage; [vmcnt(4)]; barrier; lgkm(0); 16 MFMA; barrier}.
//   Stage ks0(u+1)@ph1, ks1(u+1)@ph3; vmcnt(4)@ph2,ph4 (never 0 mid-loop).
#define BUFB 49152
#define TILEB 65536
#define LDS2 131072

using f32x4 = __attribute__((ext_vector_type(4))) float;
using s16x8 = __attribute__((ext_vector_type(8))) short;

__device__ __forceinline__ void gld_lds16(const void* g, void* l) {
    __builtin_amdgcn_global_load_lds(
        (const __attribute__((address_space(1))) void*)g,
        (__attribute__((address_space(3))) void*)l,
        16, 0, 0);
}

__device__ __forceinline__ f32x4 MFMA(s16x8 a, s16x8 b, f32x4 c) {
    return __builtin_amdgcn_mfma_f32_16x16x32_bf16(a, b, c, 0, 0, 0);
}

// ------------- prep: all f32->bf16 conversions + mask/ts, one launch ----
__global__ __launch_bounds__(256) void prep(
    const float* __restrict__ sp, const float* __restrict__ we,
    const float* __restrict__ wp, const int* __restrict__ mIn,
    const int* __restrict__ tIn,
    __hip_bfloat16* __restrict__ spB, __hip_bfloat16* __restrict__ weB,
    __hip_bfloat16* __restrict__ wpB, float* __restrict__ out) {
    int id = blockIdx.x * 256 + threadIdx.x;
    const float* src; __hip_bfloat16* dst; int idx;
    if (id < 1572864)       { src = sp; dst = spB; idx = id; }
    else if (id < 3932160)  { src = we; dst = weB; idx = id - 1572864; }
    else if (id < 5505024)  { src = wp; dst = wpB; idx = id - 3932160; }
    else {
        int i = id - 5505024;
        if (i < B_ * L_) {
            int b = i / L_, l = i % L_;
            const int* mb = mIn + b * T_ + 2 * l;
            int m = mb[0] * mb[1] * mb[2] * mb[3];
            const size_t offM = (size_t)B_ * L_ * H_;
            out[offM + i] = (float)m;
            out[offM + (size_t)B_ * L_ + i] = (float)tIn[b * T_ + l];
        }
        return;
    }
    float4 v = reinterpret_cast<const float4*>(src)[idx];
    __hip_bfloat16 o[4] = {__float2bfloat16(v.x), __float2bfloat16(v.y),
                           __float2bfloat16(v.z), __float2bfloat16(v.w)};
    reinterpret_cast<ushort4*>(dst)[idx] = *reinterpret_cast<ushort4*>(o);
}

// ======================= gemm1 engine (r3, 188us config) =================
__device__ __forceinline__ void tile_compute(const char* la, const char* lb,
                                             f32x4 (&acc)[4][4],
                                             int rA, int rB, int g) {
    const int sxA = rA & 7, sxB = rB & 7;
    s16x8 af0[4], bf0[4], af1[4], bf1[4];
    #pragma unroll
    for (int mi = 0; mi < 4; ++mi)
        af0[mi] = *(const s16x8*)(la + rA * 128 + mi * 2048 + ((g ^ sxA) << 4));
    #pragma unroll
    for (int ni = 0; ni < 4; ++ni)
        bf0[ni] = *(const s16x8*)(lb + rB * 128 + ni * 2048 + ((g ^ sxB) << 4));
    #pragma unroll
    for (int mi = 0; mi < 4; ++mi)
        af1[mi] = *(const s16x8*)(la + rA * 128 + mi * 2048 + (((4 + g) ^ sxA) << 4));
    #pragma unroll
    for (int ni = 0; ni < 4; ++ni)
        bf1[ni] = *(const s16x8*)(lb + rB * 128 + ni * 2048 + (((4 + g) ^ sxB) << 4));
    asm volatile("s_waitcnt lgkmcnt(8)" ::: "memory");
    __builtin_amdgcn_sched_barrier(0);
    __builtin_amdgcn_s_setprio(1);
    #pragma unroll
    for (int mi = 0; mi < 4; ++mi)
        #pragma unroll
        for (int ni = 0; ni < 4; ++ni)
            acc[mi][ni] = MFMA(af0[mi], bf0[ni], acc[mi][ni]);
    __builtin_amdgcn_s_setprio(0);
    asm volatile("s_waitcnt lgkmcnt(0)" ::: "memory");
    __builtin_amdgcn_sched_barrier(0);
    __builtin_amdgcn_s_setprio(1);
    #pragma unroll
    for (int mi = 0; mi < 4; ++mi)
        #pragma unroll
        for (int ni = 0; ni < 4; ++ni)
            acc[mi][ni] = MFMA(af1[mi], bf1[ni], acc[mi][ni]);
    __builtin_amdgcn_s_setprio(0);
}

// grid 768 1-D XCD batch-major; 512 threads (4Mx2N waves, 64x64 wave tile).
__global__ __launch_bounds__(512, 2) void gemm1_embed(
    const __hip_bfloat16* __restrict__ Sp,
    const __hip_bfloat16* __restrict__ We,
    const float* __restrict__ bEmb,
    const int* __restrict__ dateIdx,
    __hip_bfloat16* __restrict__ X1) {
    extern __shared__ __align__(16) char lds[];
    const int tid  = threadIdx.x;
    const int lane = tid & 63, wid = tid >> 6;
    const int wr = wid >> 1, wc = wid & 1;
    const int id   = blockIdx.x;             // 0..767
    const int xcd  = id & 7, slot = id >> 3; // slot 0..95
    const int b    = xcd * 4 + slot / 24;
    const int tile = slot % 24;
    const int m0   = (tile % 2) * 256;
    const int n0   = (tile / 2) * 128;
    const int didx = dateIdx[b];
    const __hip_bfloat16* A  = Sp + (size_t)b * T_ * C_;
    const __hip_bfloat16* Bm = We + (size_t)didx * D_ * C_;
    const int KT = C_ / 64;              // 6

    auto stage = [&](int kt, int buf) {
        char* lA = lds + buf * BUFB;
        char* lB = lA + 32768;
        int k0 = kt * 64;
        #pragma unroll
        for (int i = 0; i < 4; ++i) {
            int p = i * 512 + tid;
            int row = p >> 3;
            int clog = (p & 7) ^ (row & 7);
            gld_lds16(A + (size_t)(m0 + row) * C_ + k0 + clog * 8,
                      lA + (i * 512 + wid * 64) * 16);
        }
        #pragma unroll
        for (int i = 0; i < 2; ++i) {
            int p = i * 512 + tid;
            int row = p >> 3;
            int clog = (p & 7) ^ (row & 7);
            gld_lds16(Bm + (size_t)(n0 + row) * C_ + k0 + clog * 8,
                      lB + (i * 512 + wid * 64) * 16);
        }
    };

    f32x4 acc[4][4] = {};
    const int rl = lane & 15, g = lane >> 4;
    const int rA = wr * 64 + rl, rB = wc * 64 + rl;

    stage(0, 0);
    stage(1, 1);
    for (int kt = 0; kt < KT - 2; ++kt) {
        stage(kt + 2, (kt + 2) % 3);
        asm volatile("s_waitcnt vmcnt(12)" ::: "memory");
        __builtin_amdgcn_s_barrier();
        const char* la = lds + (kt % 3) * BUFB;
        tile_compute(la, la + 32768, acc, rA, rB, g);
        __builtin_amdgcn_s_barrier();
    }
    asm volatile("s_waitcnt vmcnt(6)" ::: "memory");
    __builtin_amdgcn_s_barrier();
    {
        const char* la = lds + ((KT - 2) % 3) * BUFB;
        tile_compute(la, la + 32768, acc, rA, rB, g);
    }
    asm volatile("s_waitcnt vmcnt(0)" ::: "memory");
    __builtin_amdgcn_s_barrier();
    {
        const char* la = lds + ((KT - 1) % 3) * BUFB;
        tile_compute(la, la + 32768, acc, rA, rB, g);
    }

    #pragma unroll
    for (int mi = 0; mi < 4; ++mi) {
        #pragma unroll
        for (int ni = 0; ni < 4; ++ni) {
            int col = n0 + wc * 64 + ni * 16 + rl;              // d
            float bg = bEmb[didx * D_ + col];
            #pragma unroll
            for (int r = 0; r < 4; ++r) {
                int row = m0 + wr * 64 + mi * 16 + g * 4 + r;   // t
                float v = acc[mi][ni][r] + bg;
                float gl = 0.5f * v * (1.0f + erff(v * 0.70710678118f)) * 32.0f;
                X1[((size_t)b * T_ + row) * D_ + col] = __float2bfloat16(gl);
            }
        }
    }
}

// ======================= gemm2: m201-style 8-barrier =====================
// grid 256 1-D XCD batch-major; split-K x2 (kh) + combine.
__global__ __launch_bounds__(512, 2) void gemm2_proj(
    const __hip_bfloat16* __restrict__ X1,
    const __hip_bfloat16* __restrict__ Wp,
    float* __restrict__ outX,                  // partial kh=0
    __hip_bfloat16* __restrict__ P1) {         // partial kh=1
    extern __shared__ __align__(16) char lds[];
    const int tid  = threadIdx.x;
    const int lane = tid & 63, wid = tid >> 6;
    const int wm = wid >> 2, wn = wid & 3;
    const int id   = blockIdx.x;               // 0..255
    const int xcd  = id & 7, slot = id >> 3;   // 0..31
    const int b    = xcd * 4 + (slot >> 3);
    const int sub  = slot & 7;
    const int kh   = sub >> 2;
    const int n0   = (sub & 3) * 256;
    const __hip_bfloat16* Xb = X1 + (size_t)b * T_ * D_;
    const int KT2 = 48;

    // Staging: K-half-major. Buffer = [A h0 16K][A h1 16K][B h0 16K][B h1 16K].
    // Half layout: [256 rows][32 bf16]; 16B chunk c (0..3), phys = c^((row>>1)&3).
    const __hip_bfloat16* aRp[2]; const __hip_bfloat16* bRp[2];
    int aDst[2];
    #pragma unroll
    for (int i = 0; i < 2; ++i) {
        int p = i * 512 + tid;          // chunk id in half, 0..1023
        int row = p >> 2;               // 0..255
        int clog = (p & 3) ^ ((row >> 1) & 3);
        int l = row < 255 ? row : 254;
        aRp[i] = Xb + (size_t)(2 * l) * D_ + clog * 8;
        bRp[i] = Wp + (size_t)(n0 + row) * KP_ + clog * 8;
        aDst[i] = (i * 512 + wid * 64) * 16;
    }
    auto kbase = [&](int kt, int h) {
        return (kt & 3) * D_ + kh * 768 + (kt >> 2) * 64 + h * 32;
    };
    auto stA = [&](int kt, int h, char* buf) {
        int ko = kbase(kt, h);
        #pragma unroll
        for (int i = 0; i < 2; ++i)
            gld_lds16(aRp[i] + ko, buf + h * 16384 + aDst[i]);
    };
    auto stB = [&](int kt, int h, char* buf) {
        int ko = kbase(kt, h);
        #pragma unroll
        for (int i = 0; i < 2; ++i)
            gld_lds16(bRp[i] + ko, buf + 32768 + h * 16384 + aDst[i]);
    };

    // Fragment byte offsets within a half region (+ks*16384 at use).
    const int rl = lane & 15, g = lane >> 4;
    int aOff[8], bOff[4];
    #pragma unroll
    for (int mi = 0; mi < 8; ++mi) {
        int r = wm * 128 + mi * 16 + rl;
        aOff[mi] = r * 64 + ((g ^ ((r >> 1) & 3)) << 4);
    }
    #pragma unroll
    for (int ni = 0; ni < 4; ++ni) {
        int r = wn * 64 + ni * 16 + rl;
        bOff[ni] = r * 64 + ((g ^ ((r >> 1) & 3)) << 4);
    }

    f32x4 acc[8][4] = {};
    // Prologue: stage tile 0 (ks0 pair first, then ks1 pair).
    stA(0, 0, lds); stB(0, 0, lds);
    stA(0, 1, lds); stB(0, 1, lds);
    asm volatile("s_waitcnt vmcnt(4)" ::: "memory");
    __builtin_amdgcn_s_barrier();

    for (int u = 0; u < KT2; ++u) {
        char* X = lds + (u & 1) * TILEB;
        char* Y = lds + ((u + 1) & 1) * TILEB;
        const bool last = (u == KT2 - 1);
        s16x8 Af[8], Bv[2];

        // ---- ph1 (ks0, nh0): reads + stage ks0(u+1)
        #pragma unroll
        for (int mi = 0; mi < 8; ++mi) Af[mi] = *(const s16x8*)(X + aOff[mi]);
        Bv[0] = *(const s16x8*)(X + 32768 + bOff[0]);
        Bv[1] = *(const s16x8*)(X + 32768 + bOff[1]);
        if (!last) { stA(u + 1, 0, Y); stB(u + 1, 0, Y); }
        __builtin_amdgcn_s_barrier();
        asm volatile("s_waitcnt lgkmcnt(0)" ::: "memory");
        __builtin_amdgcn_sched_barrier(0);
        __builtin_amdgcn_s_setprio(1);
        #pragma unroll
        for (int mi = 0; mi < 8; ++mi) {
            acc[mi][0] = MFMA(Af[mi], Bv[0], acc[mi][0]);
            acc[mi][1] = MFMA(Af[mi], Bv[1], acc[mi][1]);
        }
        __builtin_amdgcn_s_setprio(0);
        __builtin_amdgcn_s_barrier();

        // ---- ph2 (ks0, nh1): reads + vmcnt(4) [guarantees ks1(u) landed]
        Bv[0] = *(const s16x8*)(X + 32768 + bOff[2]);
        Bv[1] = *(const s16x8*)(X + 32768 + bOff[3]);
        if (last) { asm volatile("s_waitcnt vmcnt(0)" ::: "memory"); }
        else      { asm volatile("s_waitcnt vmcnt(4)" ::: "memory"); }
        __builtin_amdgcn_s_barrier();
        asm volatile("s_waitcnt lgkmcnt(0)" ::: "memory");
        __builtin_amdgcn_sched_barrier(0);
        __builtin_amdgcn_s_setprio(1);
        #pragma unroll
        for (int mi = 0; mi < 8; ++mi) {
            acc[mi][2] = MFMA(Af[mi], Bv[0], acc[mi][2]);
            acc[mi][3] = MFMA(Af[mi], Bv[1], acc[mi][3]);
        }
        __builtin_amdgcn_s_setprio(0);
        __builtin_amdgcn_s_barrier();

        // ---- ph3 (ks1, nh0): reads + stage ks1(u+1)
        #pragma unroll
        for (int mi = 0; mi < 8; ++mi) Af[mi] = *(const s16x8*)(X + 16384 + aOff[mi]);
        Bv[0] = *(const s16x8*)(X + 49152 + bOff[0]);
        Bv[1] = *(const s16x8*)(X + 49152 + bOff[1]);
        if (!last) { stA(u + 1, 1, Y); stB(u + 1, 1, Y); }
        __builtin_amdgcn_s_barrier();
        asm volatile("s_waitcnt lgkmcnt(0)" ::: "memory");
        __builtin_amdgcn_sched_barrier(0);
        __builtin_amdgcn_s_setprio(1);
        #pragma unroll
        for (int mi = 0; mi < 8; ++mi) {
            acc[mi][0] = MFMA(Af[mi], Bv[0], acc[mi][0]);
            acc[mi][1] = MFMA(Af[mi], Bv[1], acc[mi][1]);
        }
        __builtin_amdgcn_s_setprio(0);
        __builtin_amdgcn_s_barrier();

        // ---- ph4 (ks1, nh1): reads + vmcnt(4) [guarantees ks0(u+1) landed]
        Bv[0] = *(const s16x8*)(X + 49152 + bOff[2]);
        Bv[1] = *(const s16x8*)(X + 49152 + bOff[3]);
        if (!last) { asm volatile("s_waitcnt vmcnt(4)" ::: "memory"); }
        __builtin_amdgcn_s_barrier();
        asm volatile("s_waitcnt lgkmcnt(0)" ::: "memory");
        __builtin_amdgcn_sched_barrier(0);
        __builtin_amdgcn_s_setprio(1);
        #pragma unroll
        for (int mi = 0; mi < 8; ++mi) {
            acc[mi][2] = MFMA(Af[mi], Bv[0], acc[mi][2]);
            acc[mi][3] = MFMA(Af[mi], Bv[1], acc[mi][3]);
        }
        __builtin_amdgcn_s_setprio(0);
        __builtin_amdgcn_s_barrier();
    }

    // epilogue: raw partial store (bias/pos added in combine)
    #pragma unroll
    for (int mi = 0; mi < 8; ++mi) {
        #pragma unroll
        for (int ni = 0; ni < 4; ++ni) {
            int h = n0 + wn * 64 + ni * 16 + rl;
            #pragma unroll
            for (int r = 0; r < 4; ++r) {
                int l = wm * 128 + mi * 16 + g * 4 + r;
                if (l < L_) {
                    size_t o = ((size_t)b * L_ + l) * H_ + h;
                    if (kh == 0) outX[o] = acc[mi][ni][r];
                    else         P1[o]  = __float2bfloat16(acc[mi][ni][r]);
                }
            }
        }
    }
}

// ---------------- combine: out = p0(out) + p1 + b_proj + pos_table[ts] ----
__global__ __launch_bounds__(256) void combine(
    const __hip_bfloat16* __restrict__ P1,
    const float* __restrict__ bProj,
    const float* __restrict__ posTab,
    const int* __restrict__ tsIn,
    float* __restrict__ outX) {
    const int l = blockIdx.x, b = blockIdx.y;
    const int h = threadIdx.x * 4;
    const size_t o4 = ((size_t)(b * L_ + l) * H_ + h) >> 2;
    const int tsv = tsIn[b * T_ + l];
    float4 v = reinterpret_cast<float4*>(outX)[o4];
    ushort4 u = reinterpret_cast<const ushort4*>(P1)[o4];
    union { unsigned ui; float f; } c0, c1, c2, c3;
    c0.ui = (unsigned)u.x << 16; c1.ui = (unsigned)u.y << 16;
    c2.ui = (unsigned)u.z << 16; c3.ui = (unsigned)u.w << 16;
    float4 bp = reinterpret_cast<const float4*>(bProj)[h >> 2];
    float4 pt = reinterpret_cast<const float4*>(posTab + (size_t)tsv * H_)[h >> 2];
    v.x += c0.f + bp.x + pt.x;
    v.y += c1.f + bp.y + pt.y;
    v.z += c2.f + bp.z + pt.z;
    v.w += c3.f + bp.w + pt.w;
    reinterpret_cast<float4*>(outX)[o4] = v;
}

extern "C" void kernel_launch(void* const* d_in, const int* in_sizes, int n_in,
                              void* d_out, int out_size, void* d_ws, size_t ws_size,
                              hipStream_t stream) {
    (void)in_sizes; (void)n_in; (void)out_size; (void)ws_size;
    const float* spikes  = (const float*)d_in[0];
    const int*   smask   = (const int*)d_in[1];
    const int*   sts     = (const int*)d_in[2];
    const int*   dateIdx = (const int*)d_in[3];
    const float* Wemb    = (const float*)d_in[4];
    const float* bEmb    = (const float*)d_in[5];
    const float* Wproj   = (const float*)d_in[6];
    const float* bProj   = (const float*)d_in[7];
    const float* posTab  = (const float*)d_in[8];
    float* out = (float*)d_out;

    // workspace layout (bytes):
    // X1 bf16   [B][T][D]  : 50331648                 @ 0
    // SpB bf16  [B][T][C]  : 12582912                 @ 50331648
    // WeB bf16  [ND][D][C] : 18874368                 @ 62914560  (dead after gemm1)
    //   P1 bf16 [B][L][H]  : 16711680                 @ 62914560  (aliases WeB)
    // WpB bf16  [H][KP]    : 12582912                 @ 81788928
    char* ws = (char*)d_ws;
    __hip_bfloat16* X1  = (__hip_bfloat16*)(ws);
    __hip_bfloat16* SpB = (__hip_bfloat16*)(ws + 50331648);
    __hip_bfloat16* WeB = (__hip_bfloat16*)(ws + 62914560);
    __hip_bfloat16* P1  = (__hip_bfloat16*)(ws + 62914560);
    __hip_bfloat16* WpB = (__hip_bfloat16*)(ws + 81788928);

    hipFuncSetAttribute((const void*)gemm1_embed,
                        hipFuncAttributeMaxDynamicSharedMemorySize, 3 * BUFB);
    hipFuncSetAttribute((const void*)gemm2_proj,
                        hipFuncAttributeMaxDynamicSharedMemorySize, LDS2);

    prep<<<21536, 256, 0, stream>>>(spikes, Wemb, Wproj, smask, sts,
                                    SpB, WeB, WpB, out);

    gemm1_embed<<<768, 512, 3 * BUFB, stream>>>(SpB, WeB, bEmb, dateIdx, X1);

    gemm2_proj<<<256, 512, LDS2, stream>>>(X1, WpB, out, P1);

    dim3 gc(L_, B_);
    combine<<<gc, 256, 0, stream>>>(P1, bProj, posTab, sts, out);
}

// Round 10
// 164.497 us; speedup vs baseline: 1.2746x; 1.0206x over previous
//
#include <hip/hip_runtime.h>
#include <hip/hip_bf16.h>

// Problem constants
#define B_    32
#define T_    512
#define C_    384
#define D_    1536      // C*MULT
#define H_    1024
#define L_    255       // (T-SIZE)/STRIDE + 1
#define KP_   6144      // SIZE*D
#define ND_   16

// gemm1: r3 engine: BM=256 BN=128 BK=64, 8 waves (4Mx2N), tri-buffer 3x48KB,
//   counted vmcnt(12). Grid 768 XCD batch-major. (kept from the 167.9us run)
// gemm2: m201 C-quadrant schedule: BM=256(l) BN=256(h) BK=64, 8 waves (2Mx4N),
//   wave tile 128x64. LDS 2 x 64KB = [Ah0|Ah1|Bh0|Bh1] x 16KB, rows [128][64]
//   bf16, swizzle chunk^(row&7). 4 phases/K64 = C-quadrants, reads 12/4/8/0;
//   A-frags held q1-q2, B01 held q1-q3, B23 held q2-q4; stage A(u+1)@q1,
//   B(u+1)@q2; vmcnt(0)@q4 (loads >=2 phases old -> ~0 exposure).
#define BUFB 49152
#define TILEB 65536
#define LDS2 131072

using f32x4 = __attribute__((ext_vector_type(4))) float;
using s16x8 = __attribute__((ext_vector_type(8))) short;

__device__ __forceinline__ void gld_lds16(const void* g, void* l) {
    __builtin_amdgcn_global_load_lds(
        (const __attribute__((address_space(1))) void*)g,
        (__attribute__((address_space(3))) void*)l,
        16, 0, 0);
}

__device__ __forceinline__ f32x4 MFMA(s16x8 a, s16x8 b, f32x4 c) {
    return __builtin_amdgcn_mfma_f32_16x16x32_bf16(a, b, c, 0, 0, 0);
}

// ------------- prep: all f32->bf16 conversions + mask/ts, one launch ----
__global__ __launch_bounds__(256) void prep(
    const float* __restrict__ sp, const float* __restrict__ we,
    const float* __restrict__ wp, const int* __restrict__ mIn,
    const int* __restrict__ tIn,
    __hip_bfloat16* __restrict__ spB, __hip_bfloat16* __restrict__ weB,
    __hip_bfloat16* __restrict__ wpB, float* __restrict__ out) {
    int id = blockIdx.x * 256 + threadIdx.x;
    const float* src; __hip_bfloat16* dst; int idx;
    if (id < 1572864)       { src = sp; dst = spB; idx = id; }
    else if (id < 3932160)  { src = we; dst = weB; idx = id - 1572864; }
    else if (id < 5505024)  { src = wp; dst = wpB; idx = id - 3932160; }
    else {
        int i = id - 5505024;
        if (i < B_ * L_) {
            int b = i / L_, l = i % L_;
            const int* mb = mIn + b * T_ + 2 * l;
            int m = mb[0] * mb[1] * mb[2] * mb[3];
            const size_t offM = (size_t)B_ * L_ * H_;
            out[offM + i] = (float)m;
            out[offM + (size_t)B_ * L_ + i] = (float)tIn[b * T_ + l];
        }
        return;
    }
    float4 v = reinterpret_cast<const float4*>(src)[idx];
    __hip_bfloat16 o[4] = {__float2bfloat16(v.x), __float2bfloat16(v.y),
                           __float2bfloat16(v.z), __float2bfloat16(v.w)};
    reinterpret_cast<ushort4*>(dst)[idx] = *reinterpret_cast<ushort4*>(o);
}

// ======================= gemm1 engine (r3/r9) ============================
__device__ __forceinline__ void tile_compute(const char* la, const char* lb,
                                             f32x4 (&acc)[4][4],
                                             int rA, int rB, int g) {
    const int sxA = rA & 7, sxB = rB & 7;
    s16x8 af0[4], bf0[4], af1[4], bf1[4];
    #pragma unroll
    for (int mi = 0; mi < 4; ++mi)
        af0[mi] = *(const s16x8*)(la + rA * 128 + mi * 2048 + ((g ^ sxA) << 4));
    #pragma unroll
    for (int ni = 0; ni < 4; ++ni)
        bf0[ni] = *(const s16x8*)(lb + rB * 128 + ni * 2048 + ((g ^ sxB) << 4));
    #pragma unroll
    for (int mi = 0; mi < 4; ++mi)
        af1[mi] = *(const s16x8*)(la + rA * 128 + mi * 2048 + (((4 + g) ^ sxA) << 4));
    #pragma unroll
    for (int ni = 0; ni < 4; ++ni)
        bf1[ni] = *(const s16x8*)(lb + rB * 128 + ni * 2048 + (((4 + g) ^ sxB) << 4));
    asm volatile("s_waitcnt lgkmcnt(8)" ::: "memory");
    __builtin_amdgcn_sched_barrier(0);
    __builtin_amdgcn_s_setprio(1);
    #pragma unroll
    for (int mi = 0; mi < 4; ++mi)
        #pragma unroll
        for (int ni = 0; ni < 4; ++ni)
            acc[mi][ni] = MFMA(af0[mi], bf0[ni], acc[mi][ni]);
    __builtin_amdgcn_s_setprio(0);
    asm volatile("s_waitcnt lgkmcnt(0)" ::: "memory");
    __builtin_amdgcn_sched_barrier(0);
    __builtin_amdgcn_s_setprio(1);
    #pragma unroll
    for (int mi = 0; mi < 4; ++mi)
        #pragma unroll
        for (int ni = 0; ni < 4; ++ni)
            acc[mi][ni] = MFMA(af1[mi], bf1[ni], acc[mi][ni]);
    __builtin_amdgcn_s_setprio(0);
}

__global__ __launch_bounds__(512, 2) void gemm1_embed(
    const __hip_bfloat16* __restrict__ Sp,
    const __hip_bfloat16* __restrict__ We,
    const float* __restrict__ bEmb,
    const int* __restrict__ dateIdx,
    __hip_bfloat16* __restrict__ X1) {
    extern __shared__ __align__(16) char lds[];
    const int tid  = threadIdx.x;
    const int lane = tid & 63, wid = tid >> 6;
    const int wr = wid >> 1, wc = wid & 1;
    const int id   = blockIdx.x;             // 0..767
    const int xcd  = id & 7, slot = id >> 3; // slot 0..95
    const int b    = xcd * 4 + slot / 24;
    const int tile = slot % 24;
    const int m0   = (tile % 2) * 256;
    const int n0   = (tile / 2) * 128;
    const int didx = dateIdx[b];
    const __hip_bfloat16* A  = Sp + (size_t)b * T_ * C_;
    const __hip_bfloat16* Bm = We + (size_t)didx * D_ * C_;
    const int KT = C_ / 64;              // 6

    auto stage = [&](int kt, int buf) {
        char* lA = lds + buf * BUFB;
        char* lB = lA + 32768;
        int k0 = kt * 64;
        #pragma unroll
        for (int i = 0; i < 4; ++i) {
            int p = i * 512 + tid;
            int row = p >> 3;
            int clog = (p & 7) ^ (row & 7);
            gld_lds16(A + (size_t)(m0 + row) * C_ + k0 + clog * 8,
                      lA + (i * 512 + wid * 64) * 16);
        }
        #pragma unroll
        for (int i = 0; i < 2; ++i) {
            int p = i * 512 + tid;
            int row = p >> 3;
            int clog = (p & 7) ^ (row & 7);
            gld_lds16(Bm + (size_t)(n0 + row) * C_ + k0 + clog * 8,
                      lB + (i * 512 + wid * 64) * 16);
        }
    };

    f32x4 acc[4][4] = {};
    const int rl = lane & 15, g = lane >> 4;
    const int rA = wr * 64 + rl, rB = wc * 64 + rl;

    stage(0, 0);
    stage(1, 1);
    for (int kt = 0; kt < KT - 2; ++kt) {
        stage(kt + 2, (kt + 2) % 3);
        asm volatile("s_waitcnt vmcnt(12)" ::: "memory");
        __builtin_amdgcn_s_barrier();
        const char* la = lds + (kt % 3) * BUFB;
        tile_compute(la, la + 32768, acc, rA, rB, g);
        __builtin_amdgcn_s_barrier();
    }
    asm volatile("s_waitcnt vmcnt(6)" ::: "memory");
    __builtin_amdgcn_s_barrier();
    {
        const char* la = lds + ((KT - 2) % 3) * BUFB;
        tile_compute(la, la + 32768, acc, rA, rB, g);
    }
    asm volatile("s_waitcnt vmcnt(0)" ::: "memory");
    __builtin_amdgcn_s_barrier();
    {
        const char* la = lds + ((KT - 1) % 3) * BUFB;
        tile_compute(la, la + 32768, acc, rA, rB, g);
    }

    #pragma unroll
    for (int mi = 0; mi < 4; ++mi) {
        #pragma unroll
        for (int ni = 0; ni < 4; ++ni) {
            int col = n0 + wc * 64 + ni * 16 + rl;              // d
            float bg = bEmb[didx * D_ + col];
            #pragma unroll
            for (int r = 0; r < 4; ++r) {
                int row = m0 + wr * 64 + mi * 16 + g * 4 + r;   // t
                float v = acc[mi][ni][r] + bg;
                float gl = 0.5f * v * (1.0f + erff(v * 0.70710678118f)) * 32.0f;
                X1[((size_t)b * T_ + row) * D_ + col] = __float2bfloat16(gl);
            }
        }
    }
}

// ======================= gemm2: C-quadrant 8-wave ========================
__global__ __launch_bounds__(512, 2) void gemm2_proj(
    const __hip_bfloat16* __restrict__ X1,
    const __hip_bfloat16* __restrict__ Wp,
    float* __restrict__ outX,                  // partial kh=0
    __hip_bfloat16* __restrict__ P1) {         // partial kh=1
    extern __shared__ __align__(16) char lds[];
    const int tid  = threadIdx.x;
    const int lane = tid & 63, wid = tid >> 6;
    const int wm = wid >> 2, wn = wid & 3;
    const int id   = blockIdx.x;               // 0..255
    const int xcd  = id & 7, slot = id >> 3;   // 0..31
    const int b    = xcd * 4 + (slot >> 3);
    const int sub  = slot & 7;
    const int kh   = sub >> 2;
    const int n0   = (sub & 3) * 256;
    const __hip_bfloat16* Xb = X1 + (size_t)b * T_ * D_;
    const int KT2 = 48;

    // staging sources (per thread) + per-wave dest bases.
    // Half-tile layout: [128 rows][64 bf16], chunk_phys = chunk_log^(row&7).
    const __hip_bfloat16* aP[2][2]; const __hip_bfloat16* bP[2][2];
    int dstB[2];
    #pragma unroll
    for (int i = 0; i < 2; ++i) {
        int p = i * 512 + tid;          // chunk id in half, 0..1023
        int row = p >> 3;               // 0..127
        int c = (p & 7) ^ (row & 7);
        dstB[i] = (i * 512 + wid * 64) * 16;
        #pragma unroll
        for (int h = 0; h < 2; ++h) {
            int la = h * 128 + row; if (la > 254) la = 254;
            aP[i][h] = Xb + (size_t)(2 * la) * D_ + c * 8;
            bP[i][h] = Wp + (size_t)(n0 + h * 128 + row) * KP_ + c * 8;
        }
    }
    auto kofs = [&](int kt) { return (kt & 3) * D_ + kh * 768 + (kt >> 2) * 64; };
    auto stageA = [&](int kt, char* buf) {
        int ko = kofs(kt);
        #pragma unroll
        for (int h = 0; h < 2; ++h)
            #pragma unroll
            for (int i = 0; i < 2; ++i)
                gld_lds16(aP[i][h] + ko, buf + h * 16384 + dstB[i]);
    };
    auto stageB = [&](int kt, char* buf) {
        int ko = kofs(kt);
        #pragma unroll
        for (int h = 0; h < 2; ++h)
            #pragma unroll
            for (int i = 0; i < 2; ++i)
                gld_lds16(bP[i][h] + ko, buf + 32768 + h * 16384 + dstB[i]);
    };

    // fragment read geometry
    const int rl = lane & 15, g = lane >> 4, sx = rl & 7;
    const int ck0 = (g ^ sx) << 4, ck1 = ((4 + g) ^ sx) << 4;
    int aRow[8], bRow[4];
    #pragma unroll
    for (int mi = 0; mi < 8; ++mi) aRow[mi] = (mi * 16 + rl) * 128;
    #pragma unroll
    for (int ni = 0; ni < 4; ++ni) bRow[ni] = ((wn & 1) * 64 + ni * 16 + rl) * 128;

    f32x4 acc[8][4] = {};
    stageA(0, lds); stageB(0, lds);
    asm volatile("s_waitcnt vmcnt(0)" ::: "memory");
    __builtin_amdgcn_s_barrier();

    for (int u = 0; u < KT2; ++u) {
        const char* Xt = lds + (u & 1) * TILEB;
        char* Y = lds + ((u & 1) ^ 1) * TILEB;
        const char* Ah = Xt + wm * 16384;
        const char* Bh = Xt + 32768 + (wn >> 1) * 16384;
        const bool last = (u == KT2 - 1);
        s16x8 A[4][2], B01[2][2], B23[2][2];

        // ---- q1: read A[0-3]+B[0-1] (12); stage A(u+1); 16 MFMA
        #pragma unroll
        for (int mi = 0; mi < 4; ++mi) {
            A[mi][0] = *(const s16x8*)(Ah + aRow[mi] + ck0);
            A[mi][1] = *(const s16x8*)(Ah + aRow[mi] + ck1);
        }
        #pragma unroll
        for (int ni = 0; ni < 2; ++ni) {
            B01[ni][0] = *(const s16x8*)(Bh + bRow[ni] + ck0);
            B01[ni][1] = *(const s16x8*)(Bh + bRow[ni] + ck1);
        }
        if (!last) stageA(u + 1, Y);
        __builtin_amdgcn_s_barrier();
        asm volatile("s_waitcnt lgkmcnt(0)" ::: "memory");
        __builtin_amdgcn_sched_barrier(0);
        __builtin_amdgcn_s_setprio(1);
        #pragma unroll
        for (int mi = 0; mi < 4; ++mi)
            #pragma unroll
            for (int ni = 0; ni < 2; ++ni)
                #pragma unroll
                for (int ks = 0; ks < 2; ++ks)
                    acc[mi][ni] = MFMA(A[mi][ks], B01[ni][ks], acc[mi][ni]);
        __builtin_amdgcn_s_setprio(0);
        __builtin_amdgcn_s_barrier();

        // ---- q2: read B[2-3] (4); stage B(u+1); 16 MFMA
        #pragma unroll
        for (int ni = 0; ni < 2; ++ni) {
            B23[ni][0] = *(const s16x8*)(Bh + bRow[2 + ni] + ck0);
            B23[ni][1] = *(const s16x8*)(Bh + bRow[2 + ni] + ck1);
        }
        if (!last) stageB(u + 1, Y);
        __builtin_amdgcn_s_barrier();
        asm volatile("s_waitcnt lgkmcnt(0)" ::: "memory");
        __builtin_amdgcn_sched_barrier(0);
        __builtin_amdgcn_s_setprio(1);
        #pragma unroll
        for (int mi = 0; mi < 4; ++mi)
            #pragma unroll
            for (int ni = 0; ni < 2; ++ni)
                #pragma unroll
                for (int ks = 0; ks < 2; ++ks)
                    acc[mi][2 + ni] = MFMA(A[mi][ks], B23[ni][ks], acc[mi][2 + ni]);
        __builtin_amdgcn_s_setprio(0);
        __builtin_amdgcn_s_barrier();

        // ---- q3: read A[4-7] (8, overwrite A regs); 16 MFMA with B01
        #pragma unroll
        for (int mi = 0; mi < 4; ++mi) {
            A[mi][0] = *(const s16x8*)(Ah + aRow[4 + mi] + ck0);
            A[mi][1] = *(const s16x8*)(Ah + aRow[4 + mi] + ck1);
        }
        __builtin_amdgcn_s_barrier();
        asm volatile("s_waitcnt lgkmcnt(0)" ::: "memory");
        __builtin_amdgcn_sched_barrier(0);
        __builtin_amdgcn_s_setprio(1);
        #pragma unroll
        for (int mi = 0; mi < 4; ++mi)
            #pragma unroll
            for (int ni = 0; ni < 2; ++ni)
                #pragma unroll
                for (int ks = 0; ks < 2; ++ks)
                    acc[4 + mi][ni] = MFMA(A[mi][ks], B01[ni][ks], acc[4 + mi][ni]);
        __builtin_amdgcn_s_setprio(0);
        __builtin_amdgcn_s_barrier();

        // ---- q4: pure MFMA (A x B23); vmcnt(0) (loads >=2 phases old); bar
        __builtin_amdgcn_s_setprio(1);
        #pragma unroll
        for (int mi = 0; mi < 4; ++mi)
            #pragma unroll
            for (int ni = 0; ni < 2; ++ni)
                #pragma unroll
                for (int ks = 0; ks < 2; ++ks)
                    acc[4 + mi][2 + ni] = MFMA(A[mi][ks], B23[ni][ks], acc[4 + mi][2 + ni]);
        __builtin_amdgcn_s_setprio(0);
        if (!last) { asm volatile("s_waitcnt vmcnt(0)" ::: "memory"); }
        __builtin_amdgcn_s_barrier();
    }

    // epilogue: raw partial store (bias/pos added in combine)
    #pragma unroll
    for (int mi = 0; mi < 8; ++mi) {
        #pragma unroll
        for (int ni = 0; ni < 4; ++ni) {
            int h = n0 + wn * 64 + ni * 16 + rl;
            #pragma unroll
            for (int r = 0; r < 4; ++r) {
                int l = wm * 128 + mi * 16 + g * 4 + r;
                if (l < L_) {
                    size_t o = ((size_t)b * L_ + l) * H_ + h;
                    if (kh == 0) outX[o] = acc[mi][ni][r];
                    else         P1[o]  = __float2bfloat16(acc[mi][ni][r]);
                }
            }
        }
    }
}

// ---------------- combine: out = p0(out) + p1 + b_proj + pos_table[ts] ----
__global__ __launch_bounds__(256) void combine(
    const __hip_bfloat16* __restrict__ P1,
    const float* __restrict__ bProj,
    const float* __restrict__ posTab,
    const int* __restrict__ tsIn,
    float* __restrict__ outX) {
    const int l = blockIdx.x, b = blockIdx.y;
    const int h = threadIdx.x * 4;
    const size_t o4 = ((size_t)(b * L_ + l) * H_ + h) >> 2;
    const int tsv = tsIn[b * T_ + l];
    float4 v = reinterpret_cast<float4*>(outX)[o4];
    ushort4 u = reinterpret_cast<const ushort4*>(P1)[o4];
    union { unsigned ui; float f; } c0, c1, c2, c3;
    c0.ui = (unsigned)u.x << 16; c1.ui = (unsigned)u.y << 16;
    c2.ui = (unsigned)u.z << 16; c3.ui = (unsigned)u.w << 16;
    float4 bp = reinterpret_cast<const float4*>(bProj)[h >> 2];
    float4 pt = reinterpret_cast<const float4*>(posTab + (size_t)tsv * H_)[h >> 2];
    v.x += c0.f + bp.x + pt.x;
    v.y += c1.f + bp.y + pt.y;
    v.z += c2.f + bp.z + pt.z;
    v.w += c3.f + bp.w + pt.w;
    reinterpret_cast<float4*>(outX)[o4] = v;
}

extern "C" void kernel_launch(void* const* d_in, const int* in_sizes, int n_in,
                              void* d_out, int out_size, void* d_ws, size_t ws_size,
                              hipStream_t stream) {
    (void)in_sizes; (void)n_in; (void)out_size; (void)ws_size;
    const float* spikes  = (const float*)d_in[0];
    const int*   smask   = (const int*)d_in[1];
    const int*   sts     = (const int*)d_in[2];
    const int*   dateIdx = (const int*)d_in[3];
    const float* Wemb    = (const float*)d_in[4];
    const float* bEmb    = (const float*)d_in[5];
    const float* Wproj   = (const float*)d_in[6];
    const float* bProj   = (const float*)d_in[7];
    const float* posTab  = (const float*)d_in[8];
    float* out = (float*)d_out;

    // workspace layout (bytes):
    // X1 bf16   [B][T][D]  : 50331648                 @ 0
    // SpB bf16  [B][T][C]  : 12582912                 @ 50331648
    // WeB bf16  [ND][D][C] : 18874368                 @ 62914560  (dead after gemm1)
    //   P1 bf16 [B][L][H]  : 16711680                 @ 62914560  (aliases WeB)
    // WpB bf16  [H][KP]    : 12582912                 @ 81788928
    char* ws = (char*)d_ws;
    __hip_bfloat16* X1  = (__hip_bfloat16*)(ws);
    __hip_bfloat16* SpB = (__hip_bfloat16*)(ws + 50331648);
    __hip_bfloat16* WeB = (__hip_bfloat16*)(ws + 62914560);
    __hip_bfloat16* P1  = (__hip_bfloat16*)(ws + 62914560);
    __hip_bfloat16* WpB = (__hip_bfloat16*)(ws + 81788928);

    hipFuncSetAttribute((const void*)gemm1_embed,
                        hipFuncAttributeMaxDynamicSharedMemorySize, 3 * BUFB);
    hipFuncSetAttribute((const void*)gemm2_proj,
                        hipFuncAttributeMaxDynamicSharedMemorySize, LDS2);

    prep<<<21536, 256, 0, stream>>>(spikes, Wemb, Wproj, smask, sts,
                                    SpB, WeB, WpB, out);

    gemm1_embed<<<768, 512, 3 * BUFB, stream>>>(SpB, WeB, bEmb, dateIdx, X1);

    gemm2_proj<<<256, 512, LDS2, stream>>>(X1, WpB, out, P1);

    dim3 gc(L_, B_);
    combine<<<gc, 256, 0, stream>>>(P1, bProj, posTab, sts, out);
}

// Round 11
// 162.807 us; speedup vs baseline: 1.2878x; 1.0104x over previous
//
#include <hip/hip_runtime.h>
#include <hip/hip_bf16.h>

// Problem constants
#define B_    32
#define T_    512
#define C_    384
#define D_    1536      // C*MULT
#define H_    1024
#define L_    255       // (T-SIZE)/STRIDE + 1
#define KP_   6144      // SIZE*D
#define ND_   16

// gemm1: r3 engine: BM=256 BN=128 BK=64, 8 waves (4Mx2N), tri-buffer 3x48KB,
//   counted vmcnt(12). Grid 768 XCD batch-major.
// gemm2: m201-faithful: C-quadrant phases + COUNTED vmcnt(6), never 0
//   mid-loop (m218: counted-vs-drain0 = +38-73%). 4 staging units/tile
//   (2 glds/thread each), each issued the phase after its region's last
//   read: A1(u+1)@q1, B0(u+2)@q3, A0(u+2)+B1(u+2)@q4; vmcnt(6)@q4 only.
#define BUFB 49152
#define TILEB 65536
#define LDS2 131072

using f32x4 = __attribute__((ext_vector_type(4))) float;
using s16x8 = __attribute__((ext_vector_type(8))) short;

__device__ __forceinline__ void gld_lds16(const void* g, void* l) {
    __builtin_amdgcn_global_load_lds(
        (const __attribute__((address_space(1))) void*)g,
        (__attribute__((address_space(3))) void*)l,
        16, 0, 0);
}

__device__ __forceinline__ f32x4 MFMA(s16x8 a, s16x8 b, f32x4 c) {
    return __builtin_amdgcn_mfma_f32_16x16x32_bf16(a, b, c, 0, 0, 0);
}

// ------------- prep: all f32->bf16 conversions + mask/ts, one launch ----
__global__ __launch_bounds__(256) void prep(
    const float* __restrict__ sp, const float* __restrict__ we,
    const float* __restrict__ wp, const int* __restrict__ mIn,
    const int* __restrict__ tIn,
    __hip_bfloat16* __restrict__ spB, __hip_bfloat16* __restrict__ weB,
    __hip_bfloat16* __restrict__ wpB, float* __restrict__ out) {
    int id = blockIdx.x * 256 + threadIdx.x;
    const float* src; __hip_bfloat16* dst; int idx;
    if (id < 1572864)       { src = sp; dst = spB; idx = id; }
    else if (id < 3932160)  { src = we; dst = weB; idx = id - 1572864; }
    else if (id < 5505024)  { src = wp; dst = wpB; idx = id - 3932160; }
    else {
        int i = id - 5505024;
        if (i < B_ * L_) {
            int b = i / L_, l = i % L_;
            const int* mb = mIn + b * T_ + 2 * l;
            int m = mb[0] * mb[1] * mb[2] * mb[3];
            const size_t offM = (size_t)B_ * L_ * H_;
            out[offM + i] = (float)m;
            out[offM + (size_t)B_ * L_ + i] = (float)tIn[b * T_ + l];
        }
        return;
    }
    float4 v = reinterpret_cast<const float4*>(src)[idx];
    __hip_bfloat16 o[4] = {__float2bfloat16(v.x), __float2bfloat16(v.y),
                           __float2bfloat16(v.z), __float2bfloat16(v.w)};
    reinterpret_cast<ushort4*>(dst)[idx] = *reinterpret_cast<ushort4*>(o);
}

// ======================= gemm1 engine (r3/r9) ============================
__device__ __forceinline__ void tile_compute(const char* la, const char* lb,
                                             f32x4 (&acc)[4][4],
                                             int rA, int rB, int g) {
    const int sxA = rA & 7, sxB = rB & 7;
    s16x8 af0[4], bf0[4], af1[4], bf1[4];
    #pragma unroll
    for (int mi = 0; mi < 4; ++mi)
        af0[mi] = *(const s16x8*)(la + rA * 128 + mi * 2048 + ((g ^ sxA) << 4));
    #pragma unroll
    for (int ni = 0; ni < 4; ++ni)
        bf0[ni] = *(const s16x8*)(lb + rB * 128 + ni * 2048 + ((g ^ sxB) << 4));
    #pragma unroll
    for (int mi = 0; mi < 4; ++mi)
        af1[mi] = *(const s16x8*)(la + rA * 128 + mi * 2048 + (((4 + g) ^ sxA) << 4));
    #pragma unroll
    for (int ni = 0; ni < 4; ++ni)
        bf1[ni] = *(const s16x8*)(lb + rB * 128 + ni * 2048 + (((4 + g) ^ sxB) << 4));
    asm volatile("s_waitcnt lgkmcnt(8)" ::: "memory");
    __builtin_amdgcn_sched_barrier(0);
    __builtin_amdgcn_s_setprio(1);
    #pragma unroll
    for (int mi = 0; mi < 4; ++mi)
        #pragma unroll
        for (int ni = 0; ni < 4; ++ni)
            acc[mi][ni] = MFMA(af0[mi], bf0[ni], acc[mi][ni]);
    __builtin_amdgcn_s_setprio(0);
    asm volatile("s_waitcnt lgkmcnt(0)" ::: "memory");
    __builtin_amdgcn_sched_barrier(0);
    __builtin_amdgcn_s_setprio(1);
    #pragma unroll
    for (int mi = 0; mi < 4; ++mi)
        #pragma unroll
        for (int ni = 0; ni < 4; ++ni)
            acc[mi][ni] = MFMA(af1[mi], bf1[ni], acc[mi][ni]);
    __builtin_amdgcn_s_setprio(0);
}

__global__ __launch_bounds__(512, 2) void gemm1_embed(
    const __hip_bfloat16* __restrict__ Sp,
    const __hip_bfloat16* __restrict__ We,
    const float* __restrict__ bEmb,
    const int* __restrict__ dateIdx,
    __hip_bfloat16* __restrict__ X1) {
    extern __shared__ __align__(16) char lds[];
    const int tid  = threadIdx.x;
    const int lane = tid & 63, wid = tid >> 6;
    const int wr = wid >> 1, wc = wid & 1;
    const int id   = blockIdx.x;             // 0..767
    const int xcd  = id & 7, slot = id >> 3; // slot 0..95
    const int b    = xcd * 4 + slot / 24;
    const int tile = slot % 24;
    const int m0   = (tile % 2) * 256;
    const int n0   = (tile / 2) * 128;
    const int didx = dateIdx[b];
    const __hip_bfloat16* A  = Sp + (size_t)b * T_ * C_;
    const __hip_bfloat16* Bm = We + (size_t)didx * D_ * C_;
    const int KT = C_ / 64;              // 6

    auto stage = [&](int kt, int buf) {
        char* lA = lds + buf * BUFB;
        char* lB = lA + 32768;
        int k0 = kt * 64;
        #pragma unroll
        for (int i = 0; i < 4; ++i) {
            int p = i * 512 + tid;
            int row = p >> 3;
            int clog = (p & 7) ^ (row & 7);
            gld_lds16(A + (size_t)(m0 + row) * C_ + k0 + clog * 8,
                      lA + (i * 512 + wid * 64) * 16);
        }
        #pragma unroll
        for (int i = 0; i < 2; ++i) {
            int p = i * 512 + tid;
            int row = p >> 3;
            int clog = (p & 7) ^ (row & 7);
            gld_lds16(Bm + (size_t)(n0 + row) * C_ + k0 + clog * 8,
                      lB + (i * 512 + wid * 64) * 16);
        }
    };

    f32x4 acc[4][4] = {};
    const int rl = lane & 15, g = lane >> 4;
    const int rA = wr * 64 + rl, rB = wc * 64 + rl;

    stage(0, 0);
    stage(1, 1);
    for (int kt = 0; kt < KT - 2; ++kt) {
        stage(kt + 2, (kt + 2) % 3);
        asm volatile("s_waitcnt vmcnt(12)" ::: "memory");
        __builtin_amdgcn_s_barrier();
        const char* la = lds + (kt % 3) * BUFB;
        tile_compute(la, la + 32768, acc, rA, rB, g);
        __builtin_amdgcn_s_barrier();
    }
    asm volatile("s_waitcnt vmcnt(6)" ::: "memory");
    __builtin_amdgcn_s_barrier();
    {
        const char* la = lds + ((KT - 2) % 3) * BUFB;
        tile_compute(la, la + 32768, acc, rA, rB, g);
    }
    asm volatile("s_waitcnt vmcnt(0)" ::: "memory");
    __builtin_amdgcn_s_barrier();
    {
        const char* la = lds + ((KT - 1) % 3) * BUFB;
        tile_compute(la, la + 32768, acc, rA, rB, g);
    }

    #pragma unroll
    for (int mi = 0; mi < 4; ++mi) {
        #pragma unroll
        for (int ni = 0; ni < 4; ++ni) {
            int col = n0 + wc * 64 + ni * 16 + rl;              // d
            float bg = bEmb[didx * D_ + col];
            #pragma unroll
            for (int r = 0; r < 4; ++r) {
                int row = m0 + wr * 64 + mi * 16 + g * 4 + r;   // t
                float v = acc[mi][ni][r] + bg;
                float gl = 0.5f * v * (1.0f + erff(v * 0.70710678118f)) * 32.0f;
                X1[((size_t)b * T_ + row) * D_ + col] = __float2bfloat16(gl);
            }
        }
    }
}

// ======================= gemm2: C-quadrant + counted vmcnt(6) ============
__global__ __launch_bounds__(512, 2) void gemm2_proj(
    const __hip_bfloat16* __restrict__ X1,
    const __hip_bfloat16* __restrict__ Wp,
    float* __restrict__ outX,                  // partial kh=0
    __hip_bfloat16* __restrict__ P1) {         // partial kh=1
    extern __shared__ __align__(16) char lds[];
    const int tid  = threadIdx.x;
    const int lane = tid & 63, wid = tid >> 6;
    const int wm = wid >> 2, wn = wid & 3;
    const int id   = blockIdx.x;               // 0..255
    const int xcd  = id & 7, slot = id >> 3;   // 0..31
    const int b    = xcd * 4 + (slot >> 3);
    const int sub  = slot & 7;
    const int kh   = sub >> 2;
    const int n0   = (sub & 3) * 256;
    const __hip_bfloat16* Xb = X1 + (size_t)b * T_ * D_;
    const int KT2 = 48;

    // staging sources; half-tile layout [128 rows][64 bf16], phys chunk =
    // log_chunk ^ (row&7). Unit = one A- or B-half = 16KB = 2 glds/thread.
    const __hip_bfloat16* aP[2][2]; const __hip_bfloat16* bP[2][2];
    int dstB[2];
    #pragma unroll
    for (int i = 0; i < 2; ++i) {
        int p = i * 512 + tid;          // chunk id in half, 0..1023
        int row = p >> 3;               // 0..127
        int c = (p & 7) ^ (row & 7);
        dstB[i] = (i * 512 + wid * 64) * 16;
        #pragma unroll
        for (int h = 0; h < 2; ++h) {
            int la = h * 128 + row; if (la > 254) la = 254;
            aP[i][h] = Xb + (size_t)(2 * la) * D_ + c * 8;
            bP[i][h] = Wp + (size_t)(n0 + h * 128 + row) * KP_ + c * 8;
        }
    }
    auto kofs = [&](int kt) { return (kt & 3) * D_ + kh * 768 + (kt >> 2) * 64; };
    auto stA = [&](int kt, int h, char* buf) {     // one A-half unit
        int ko = kofs(kt);
        #pragma unroll
        for (int i = 0; i < 2; ++i)
            gld_lds16(aP[i][h] + ko, buf + h * 16384 + dstB[i]);
    };
    auto stB = [&](int kt, int h, char* buf) {     // one B-half unit
        int ko = kofs(kt);
        #pragma unroll
        for (int i = 0; i < 2; ++i)
            gld_lds16(bP[i][h] + ko, buf + 32768 + h * 16384 + dstB[i]);
    };

    // fragment read geometry
    const int rl = lane & 15, g = lane >> 4, sx = rl & 7;
    const int ck0 = (g ^ sx) << 4, ck1 = ((4 + g) ^ sx) << 4;
    int aRow[8], bRow[4];
    #pragma unroll
    for (int mi = 0; mi < 8; ++mi) aRow[mi] = (mi * 16 + rl) * 128;
    #pragma unroll
    for (int ni = 0; ni < 4; ++ni) bRow[ni] = ((wn & 1) * 64 + ni * 16 + rl) * 128;

    f32x4 acc[8][4] = {};
    // Prologue: tile0 all 4 units -> buf0; tile1 B0,A0,B1 -> buf1.
    // (A1(1) is staged at q1(0).)  vmcnt(6) leaves tile1's 3 units in flight.
    stB(0, 0, lds); stA(0, 0, lds); stB(0, 1, lds); stA(0, 1, lds);
    stB(1, 0, lds + TILEB); stA(1, 0, lds + TILEB); stB(1, 1, lds + TILEB);
    asm volatile("s_waitcnt vmcnt(6)" ::: "memory");
    __builtin_amdgcn_s_barrier();

    for (int u = 0; u < KT2; ++u) {
        const char* Xt = lds + (u & 1) * TILEB;
        char* Y = lds + ((u & 1) ^ 1) * TILEB;   // buffer of tile u+1
        char* Xw = lds + (u & 1) * TILEB;        // refill for tile u+2
        const char* Ah = Xt + wm * 16384;
        const char* Bh = Xt + 32768 + (wn >> 1) * 16384;
        s16x8 A[4][2], B01[2][2], B23[2][2];

        // ---- q1: read A[0-3]+B[0-1] (12); stage A1(u+1)->Y; 16 MFMA
        #pragma unroll
        for (int mi = 0; mi < 4; ++mi) {
            A[mi][0] = *(const s16x8*)(Ah + aRow[mi] + ck0);
            A[mi][1] = *(const s16x8*)(Ah + aRow[mi] + ck1);
        }
        #pragma unroll
        for (int ni = 0; ni < 2; ++ni) {
            B01[ni][0] = *(const s16x8*)(Bh + bRow[ni] + ck0);
            B01[ni][1] = *(const s16x8*)(Bh + bRow[ni] + ck1);
        }
        if (u + 1 < KT2) stA(u + 1, 1, Y);
        __builtin_amdgcn_s_barrier();
        asm volatile("s_waitcnt lgkmcnt(0)" ::: "memory");
        __builtin_amdgcn_sched_barrier(0);
        __builtin_amdgcn_s_setprio(1);
        #pragma unroll
        for (int mi = 0; mi < 4; ++mi)
            #pragma unroll
            for (int ni = 0; ni < 2; ++ni)
                #pragma unroll
                for (int ks = 0; ks < 2; ++ks)
                    acc[mi][ni] = MFMA(A[mi][ks], B01[ni][ks], acc[mi][ni]);
        __builtin_amdgcn_s_setprio(0);
        __builtin_amdgcn_s_barrier();

        // ---- q2: read B[2-3] (4); 16 MFMA  (B fully read after this bar)
        #pragma unroll
        for (int ni = 0; ni < 2; ++ni) {
            B23[ni][0] = *(const s16x8*)(Bh + bRow[2 + ni] + ck0);
            B23[ni][1] = *(const s16x8*)(Bh + bRow[2 + ni] + ck1);
        }
        __builtin_amdgcn_s_barrier();
        asm volatile("s_waitcnt lgkmcnt(0)" ::: "memory");
        __builtin_amdgcn_sched_barrier(0);
        __builtin_amdgcn_s_setprio(1);
        #pragma unroll
        for (int mi = 0; mi < 4; ++mi)
            #pragma unroll
            for (int ni = 0; ni < 2; ++ni)
                #pragma unroll
                for (int ks = 0; ks < 2; ++ks)
                    acc[mi][2 + ni] = MFMA(A[mi][ks], B23[ni][ks], acc[mi][2 + ni]);
        __builtin_amdgcn_s_setprio(0);
        __builtin_amdgcn_s_barrier();

        // ---- q3: read A[4-7] (8); stage B0(u+2)->X; 16 MFMA with B01
        #pragma unroll
        for (int mi = 0; mi < 4; ++mi) {
            A[mi][0] = *(const s16x8*)(Ah + aRow[4 + mi] + ck0);
            A[mi][1] = *(const s16x8*)(Ah + aRow[4 + mi] + ck1);
        }
        if (u + 2 < KT2) stB(u + 2, 0, Xw);
        __builtin_amdgcn_s_barrier();
        asm volatile("s_waitcnt lgkmcnt(0)" ::: "memory");
        __builtin_amdgcn_sched_barrier(0);
        __builtin_amdgcn_s_setprio(1);
        #pragma unroll
        for (int mi = 0; mi < 4; ++mi)
            #pragma unroll
            for (int ni = 0; ni < 2; ++ni)
                #pragma unroll
                for (int ks = 0; ks < 2; ++ks)
                    acc[4 + mi][ni] = MFMA(A[mi][ks], B01[ni][ks], acc[4 + mi][ni]);
        __builtin_amdgcn_s_setprio(0);
        __builtin_amdgcn_s_barrier();

        // ---- q4: stage A0(u+2)+B1(u+2)->X; pure 16 MFMA; vmcnt(6); bar
        if (u + 2 < KT2) { stA(u + 2, 0, Xw); stB(u + 2, 1, Xw); }
        __builtin_amdgcn_s_setprio(1);
        #pragma unroll
        for (int mi = 0; mi < 4; ++mi)
            #pragma unroll
            for (int ni = 0; ni < 2; ++ni)
                #pragma unroll
                for (int ks = 0; ks < 2; ++ks)
                    acc[4 + mi][2 + ni] = MFMA(A[mi][ks], B23[ni][ks], acc[4 + mi][2 + ni]);
        __builtin_amdgcn_s_setprio(0);
        if (u < KT2 - 2) { asm volatile("s_waitcnt vmcnt(6)" ::: "memory"); }
        else             { asm volatile("s_waitcnt vmcnt(0)" ::: "memory"); }
        __builtin_amdgcn_s_barrier();
    }

    // epilogue: raw partial store (bias/pos added in combine)
    #pragma unroll
    for (int mi = 0; mi < 8; ++mi) {
        #pragma unroll
        for (int ni = 0; ni < 4; ++ni) {
            int h = n0 + wn * 64 + ni * 16 + rl;
            #pragma unroll
            for (int r = 0; r < 4; ++r) {
                int l = wm * 128 + mi * 16 + g * 4 + r;
                if (l < L_) {
                    size_t o = ((size_t)b * L_ + l) * H_ + h;
                    if (kh == 0) outX[o] = acc[mi][ni][r];
                    else         P1[o]  = __float2bfloat16(acc[mi][ni][r]);
                }
            }
        }
    }
}

// ---------------- combine: out = p0(out) + p1 + b_proj + pos_table[ts] ----
__global__ __launch_bounds__(256) void combine(
    const __hip_bfloat16* __restrict__ P1,
    const float* __restrict__ bProj,
    const float* __restrict__ posTab,
    const int* __restrict__ tsIn,
    float* __restrict__ outX) {
    const int l = blockIdx.x, b = blockIdx.y;
    const int h = threadIdx.x * 4;
    const size_t o4 = ((size_t)(b * L_ + l) * H_ + h) >> 2;
    const int tsv = tsIn[b * T_ + l];
    float4 v = reinterpret_cast<float4*>(outX)[o4];
    ushort4 u = reinterpret_cast<const ushort4*>(P1)[o4];
    union { unsigned ui; float f; } c0, c1, c2, c3;
    c0.ui = (unsigned)u.x << 16; c1.ui = (unsigned)u.y << 16;
    c2.ui = (unsigned)u.z << 16; c3.ui = (unsigned)u.w << 16;
    float4 bp = reinterpret_cast<const float4*>(bProj)[h >> 2];
    float4 pt = reinterpret_cast<const float4*>(posTab + (size_t)tsv * H_)[h >> 2];
    v.x += c0.f + bp.x + pt.x;
    v.y += c1.f + bp.y + pt.y;
    v.z += c2.f + bp.z + pt.z;
    v.w += c3.f + bp.w + pt.w;
    reinterpret_cast<float4*>(outX)[o4] = v;
}

extern "C" void kernel_launch(void* const* d_in, const int* in_sizes, int n_in,
                              void* d_out, int out_size, void* d_ws, size_t ws_size,
                              hipStream_t stream) {
    (void)in_sizes; (void)n_in; (void)out_size; (void)ws_size;
    const float* spikes  = (const float*)d_in[0];
    const int*   smask   = (const int*)d_in[1];
    const int*   sts     = (const int*)d_in[2];
    const int*   dateIdx = (const int*)d_in[3];
    const float* Wemb    = (const float*)d_in[4];
    const float* bEmb    = (const float*)d_in[5];
    const float* Wproj   = (const float*)d_in[6];
    const float* bProj   = (const float*)d_in[7];
    const float* posTab  = (const float*)d_in[8];
    float* out = (float*)d_out;

    // workspace layout (bytes):
    // X1 bf16   [B][T][D]  : 50331648                 @ 0
    // SpB bf16  [B][T][C]  : 12582912                 @ 50331648
    // WeB bf16  [ND][D][C] : 18874368                 @ 62914560  (dead after gemm1)
    //   P1 bf16 [B][L][H]  : 16711680                 @ 62914560  (aliases WeB)
    // WpB bf16  [H][KP]    : 12582912                 @ 81788928
    char* ws = (char*)d_ws;
    __hip_bfloat16* X1  = (__hip_bfloat16*)(ws);
    __hip_bfloat16* SpB = (__hip_bfloat16*)(ws + 50331648);
    __hip_bfloat16* WeB = (__hip_bfloat16*)(ws + 62914560);
    __hip_bfloat16* P1  = (__hip_bfloat16*)(ws + 62914560);
    __hip_bfloat16* WpB = (__hip_bfloat16*)(ws + 81788928);

    hipFuncSetAttribute((const void*)gemm1_embed,
                        hipFuncAttributeMaxDynamicSharedMemorySize, 3 * BUFB);
    hipFuncSetAttribute((const void*)gemm2_proj,
                        hipFuncAttributeMaxDynamicSharedMemorySize, LDS2);

    prep<<<21536, 256, 0, stream>>>(spikes, Wemb, Wproj, smask, sts,
                                    SpB, WeB, WpB, out);

    gemm1_embed<<<768, 512, 3 * BUFB, stream>>>(SpB, WeB, bEmb, dateIdx, X1);

    gemm2_proj<<<256, 512, LDS2, stream>>>(X1, WpB, out, P1);

    dim3 gc(L_, B_);
    combine<<<gc, 256, 0, stream>>>(P1, bProj, posTab, sts, out);
}

// Round 12
// 148.891 us; speedup vs baseline: 1.4082x; 1.0935x over previous
//
#include <hip/hip_runtime.h>
#include <hip/hip_bf16.h>

// Problem constants
#define B_    32
#define T_    512
#define C_    384
#define D_    1536      // C*MULT
#define H_    1024
#define L_    255       // (T-SIZE)/STRIDE + 1
#define KP_   6144      // SIZE*D
#define ND_   16

// gemm1: r3 engine (bf16): BM=256 BN=128 BK=64, 8 waves, tri-buffer 3x48KB,
//   counted vmcnt(12); epilogue now writes X1 as fp8 e4m3.
// gemm2: MX-fp8 K=128 (mfma_scale_f32_16x16x128_f8f6f4, fmt=fp8, scales
//   A=1.0 (0x7F), B=2^-4 (0x7B; Wp pre-scaled x16)). BM=256(l) BN=256(h)
//   BK=128, 8 waves (2Mx4N), wave tile 128x64. C-quadrant phases + counted
//   vmcnt(6) ring (r11-verified). LDS 2 x 64KB = [Ah0|Ah1|Bh0|Bh1] x 16KB,
//   half = [128 rows][128 fp8], swizzle chunk^(row&7). KT2 = 24 per kh.
#define BUFB 49152
#define TILEB 65536
#define LDS2 131072

using f32x4 = __attribute__((ext_vector_type(4))) float;
using s16x8 = __attribute__((ext_vector_type(8))) short;
using i32x4 = __attribute__((ext_vector_type(4))) int;
using i32x8 = __attribute__((ext_vector_type(8))) int;

__device__ __forceinline__ void gld_lds16(const void* g, void* l) {
    __builtin_amdgcn_global_load_lds(
        (const __attribute__((address_space(1))) void*)g,
        (__attribute__((address_space(3))) void*)l,
        16, 0, 0);
}

__device__ __forceinline__ f32x4 MFMA(s16x8 a, s16x8 b, f32x4 c) {
    return __builtin_amdgcn_mfma_f32_16x16x32_bf16(a, b, c, 0, 0, 0);
}

// MX-fp8 K=128 MFMA: A fmt fp8 (cbsz=0), B fmt fp8 (blgp=0),
// scale_a = 1.0 (e8m0 127 replicated), scale_b = 2^-4 (e8m0 123 replicated).
__device__ __forceinline__ f32x4 MFMA8(i32x8 a, i32x8 b, f32x4 c) {
    return __builtin_amdgcn_mfma_scale_f32_16x16x128_f8f6f4(
        a, b, c, 0, 0, 0, 0x7F7F7F7F, 0, 0x7B7B7B7B);
}

// ------------- prep: conversions + mask/ts, one launch ------------------
// sp -> bf16, we -> bf16, wp -> fp8 e4m3 scaled x16, mask/ts tail.
__global__ __launch_bounds__(256) void prep(
    const float* __restrict__ sp, const float* __restrict__ we,
    const float* __restrict__ wp, const int* __restrict__ mIn,
    const int* __restrict__ tIn,
    __hip_bfloat16* __restrict__ spB, __hip_bfloat16* __restrict__ weB,
    unsigned char* __restrict__ wp8, float* __restrict__ out) {
    int id = blockIdx.x * 256 + threadIdx.x;
    if (id < 3932160) {
        const float* src; __hip_bfloat16* dst; int idx;
        if (id < 1572864) { src = sp; dst = spB; idx = id; }
        else              { src = we; dst = weB; idx = id - 1572864; }
        float4 v = reinterpret_cast<const float4*>(src)[idx];
        __hip_bfloat16 o[4] = {__float2bfloat16(v.x), __float2bfloat16(v.y),
                               __float2bfloat16(v.z), __float2bfloat16(v.w)};
        reinterpret_cast<ushort4*>(dst)[idx] = *reinterpret_cast<ushort4*>(o);
    } else if (id < 5505024) {
        int idx = id - 3932160;
        float4 v = reinterpret_cast<const float4*>(wp)[idx];
        int w = __builtin_amdgcn_cvt_pk_fp8_f32(v.x * 16.f, v.y * 16.f, 0, false);
        w = __builtin_amdgcn_cvt_pk_fp8_f32(v.z * 16.f, v.w * 16.f, w, true);
        reinterpret_cast<int*>(wp8)[idx] = w;
    } else {
        int i = id - 5505024;
        if (i < B_ * L_) {
            int b = i / L_, l = i % L_;
            const int* mb = mIn + b * T_ + 2 * l;
            int m = mb[0] * mb[1] * mb[2] * mb[3];
            const size_t offM = (size_t)B_ * L_ * H_;
            out[offM + i] = (float)m;
            out[offM + (size_t)B_ * L_ + i] = (float)tIn[b * T_ + l];
        }
    }
}

// ======================= gemm1 engine (r3/r9, bf16) ======================
__device__ __forceinline__ void tile_compute(const char* la, const char* lb,
                                             f32x4 (&acc)[4][4],
                                             int rA, int rB, int g) {
    const int sxA = rA & 7, sxB = rB & 7;
    s16x8 af0[4], bf0[4], af1[4], bf1[4];
    #pragma unroll
    for (int mi = 0; mi < 4; ++mi)
        af0[mi] = *(const s16x8*)(la + rA * 128 + mi * 2048 + ((g ^ sxA) << 4));
    #pragma unroll
    for (int ni = 0; ni < 4; ++ni)
        bf0[ni] = *(const s16x8*)(lb + rB * 128 + ni * 2048 + ((g ^ sxB) << 4));
    #pragma unroll
    for (int mi = 0; mi < 4; ++mi)
        af1[mi] = *(const s16x8*)(la + rA * 128 + mi * 2048 + (((4 + g) ^ sxA) << 4));
    #pragma unroll
    for (int ni = 0; ni < 4; ++ni)
        bf1[ni] = *(const s16x8*)(lb + rB * 128 + ni * 2048 + (((4 + g) ^ sxB) << 4));
    asm volatile("s_waitcnt lgkmcnt(8)" ::: "memory");
    __builtin_amdgcn_sched_barrier(0);
    __builtin_amdgcn_s_setprio(1);
    #pragma unroll
    for (int mi = 0; mi < 4; ++mi)
        #pragma unroll
        for (int ni = 0; ni < 4; ++ni)
            acc[mi][ni] = MFMA(af0[mi], bf0[ni], acc[mi][ni]);
    __builtin_amdgcn_s_setprio(0);
    asm volatile("s_waitcnt lgkmcnt(0)" ::: "memory");
    __builtin_amdgcn_sched_barrier(0);
    __builtin_amdgcn_s_setprio(1);
    #pragma unroll
    for (int mi = 0; mi < 4; ++mi)
        #pragma unroll
        for (int ni = 0; ni < 4; ++ni)
            acc[mi][ni] = MFMA(af1[mi], bf1[ni], acc[mi][ni]);
    __builtin_amdgcn_s_setprio(0);
}

__global__ __launch_bounds__(512, 2) void gemm1_embed(
    const __hip_bfloat16* __restrict__ Sp,
    const __hip_bfloat16* __restrict__ We,
    const float* __restrict__ bEmb,
    const int* __restrict__ dateIdx,
    unsigned char* __restrict__ X18) {
    extern __shared__ __align__(16) char lds[];
    const int tid  = threadIdx.x;
    const int lane = tid & 63, wid = tid >> 6;
    const int wr = wid >> 1, wc = wid & 1;
    const int id   = blockIdx.x;             // 0..767
    const int xcd  = id & 7, slot = id >> 3; // slot 0..95
    const int b    = xcd * 4 + slot / 24;
    const int tile = slot % 24;
    const int m0   = (tile % 2) * 256;
    const int n0   = (tile / 2) * 128;
    const int didx = dateIdx[b];
    const __hip_bfloat16* A  = Sp + (size_t)b * T_ * C_;
    const __hip_bfloat16* Bm = We + (size_t)didx * D_ * C_;
    const int KT = C_ / 64;              // 6

    auto stage = [&](int kt, int buf) {
        char* lA = lds + buf * BUFB;
        char* lB = lA + 32768;
        int k0 = kt * 64;
        #pragma unroll
        for (int i = 0; i < 4; ++i) {
            int p = i * 512 + tid;
            int row = p >> 3;
            int clog = (p & 7) ^ (row & 7);
            gld_lds16(A + (size_t)(m0 + row) * C_ + k0 + clog * 8,
                      lA + (i * 512 + wid * 64) * 16);
        }
        #pragma unroll
        for (int i = 0; i < 2; ++i) {
            int p = i * 512 + tid;
            int row = p >> 3;
            int clog = (p & 7) ^ (row & 7);
            gld_lds16(Bm + (size_t)(n0 + row) * C_ + k0 + clog * 8,
                      lB + (i * 512 + wid * 64) * 16);
        }
    };

    f32x4 acc[4][4] = {};
    const int rl = lane & 15, g = lane >> 4;
    const int rA = wr * 64 + rl, rB = wc * 64 + rl;

    stage(0, 0);
    stage(1, 1);
    for (int kt = 0; kt < KT - 2; ++kt) {
        stage(kt + 2, (kt + 2) % 3);
        asm volatile("s_waitcnt vmcnt(12)" ::: "memory");
        __builtin_amdgcn_s_barrier();
        const char* la = lds + (kt % 3) * BUFB;
        tile_compute(la, la + 32768, acc, rA, rB, g);
        __builtin_amdgcn_s_barrier();
    }
    asm volatile("s_waitcnt vmcnt(6)" ::: "memory");
    __builtin_amdgcn_s_barrier();
    {
        const char* la = lds + ((KT - 2) % 3) * BUFB;
        tile_compute(la, la + 32768, acc, rA, rB, g);
    }
    asm volatile("s_waitcnt vmcnt(0)" ::: "memory");
    __builtin_amdgcn_s_barrier();
    {
        const char* la = lds + ((KT - 1) % 3) * BUFB;
        tile_compute(la, la + 32768, acc, rA, rB, g);
    }

    // epilogue: + bias, exact gelu, * 32, store fp8 e4m3
    #pragma unroll
    for (int mi = 0; mi < 4; ++mi) {
        #pragma unroll
        for (int ni = 0; ni < 4; ++ni) {
            int col = n0 + wc * 64 + ni * 16 + rl;              // d
            float bg = bEmb[didx * D_ + col];
            #pragma unroll
            for (int r = 0; r < 4; ++r) {
                int row = m0 + wr * 64 + mi * 16 + g * 4 + r;   // t
                float v = acc[mi][ni][r] + bg;
                float gl = 0.5f * v * (1.0f + erff(v * 0.70710678118f)) * 32.0f;
                int pk = __builtin_amdgcn_cvt_pk_fp8_f32(gl, gl, 0, false);
                X18[((size_t)b * T_ + row) * D_ + col] = (unsigned char)pk;
            }
        }
    }
}

// ======================= gemm2: MX-fp8 K128, C-quadrant + vmcnt(6) =======
__global__ __launch_bounds__(512, 2) void gemm2_proj(
    const unsigned char* __restrict__ X18,     // [B][T][D] fp8
    const unsigned char* __restrict__ Wp8,     // [H][KP] fp8 (x16 scaled)
    float* __restrict__ outX,                  // partial kh=0
    __hip_bfloat16* __restrict__ P1) {         // partial kh=1
    extern __shared__ __align__(16) char lds[];
    const int tid  = threadIdx.x;
    const int lane = tid & 63, wid = tid >> 6;
    const int wm = wid >> 2, wn = wid & 3;
    const int id   = blockIdx.x;               // 0..255
    const int xcd  = id & 7, slot = id >> 3;   // 0..31
    const int b    = xcd * 4 + (slot >> 3);
    const int sub  = slot & 7;
    const int kh   = sub >> 2;
    const int n0   = (sub & 3) * 256;
    const unsigned char* Xb = X18 + (size_t)b * T_ * D_;
    const int KT2 = 24;                        // K128 tiles per half

    // staging: half = [128 rows][128 fp8] = 16KB; chunk = 16B; phys = log^(row&7)
    const unsigned char* aP[2][2]; const unsigned char* bP[2][2];
    int dstB[2];
    #pragma unroll
    for (int i = 0; i < 2; ++i) {
        int p = i * 512 + tid;          // chunk id in half, 0..1023
        int row = p >> 3;               // 0..127
        int c = (p & 7) ^ (row & 7);
        dstB[i] = (i * 512 + wid * 64) * 16;
        #pragma unroll
        for (int h = 0; h < 2; ++h) {
            int la = h * 128 + row; if (la > 254) la = 254;
            aP[i][h] = Xb + (size_t)(2 * la) * D_ + c * 16;
            bP[i][h] = Wp8 + (size_t)(n0 + h * 128 + row) * KP_ + c * 16;
        }
    }
    auto kofs = [&](int kt) { return (kt & 3) * D_ + kh * 768 + (kt >> 2) * 128; };
    auto stA = [&](int kt, int h, char* buf) {     // one A-half unit (16KB)
        int ko = kofs(kt);
        #pragma unroll
        for (int i = 0; i < 2; ++i)
            gld_lds16(aP[i][h] + ko, buf + h * 16384 + dstB[i]);
    };
    auto stB = [&](int kt, int h, char* buf) {     // one B-half unit (16KB)
        int ko = kofs(kt);
        #pragma unroll
        for (int i = 0; i < 2; ++i)
            gld_lds16(bP[i][h] + ko, buf + 32768 + h * 16384 + dstB[i]);
    };

    // fragment read geometry: lane reads 32B (chunks 2g, 2g+1) of its row
    const int rl = lane & 15, g = lane >> 4, sx = rl & 7;
    const int ck0 = (((g << 1)) ^ sx) << 4;
    const int ck1 = (((g << 1) | 1) ^ sx) << 4;
    int aRow[8], bRow[4];
    #pragma unroll
    for (int mi = 0; mi < 8; ++mi) aRow[mi] = (mi * 16 + rl) * 128;
    #pragma unroll
    for (int ni = 0; ni < 4; ++ni) bRow[ni] = ((wn & 1) * 64 + ni * 16 + rl) * 128;

    f32x4 acc[8][4] = {};
    // Prologue: tile0 all 4 units -> buf0; tile1 B0,A0,B1 -> buf1.
    stB(0, 0, lds); stA(0, 0, lds); stB(0, 1, lds); stA(0, 1, lds);
    stB(1, 0, lds + TILEB); stA(1, 0, lds + TILEB); stB(1, 1, lds + TILEB);
    asm volatile("s_waitcnt vmcnt(6)" ::: "memory");
    __builtin_amdgcn_s_barrier();

    for (int u = 0; u < KT2; ++u) {
        const char* Xt = lds + (u & 1) * TILEB;
        char* Y = lds + ((u & 1) ^ 1) * TILEB;   // buffer of tile u+1
        char* Xw = lds + (u & 1) * TILEB;        // refill for tile u+2
        const char* Ah = Xt + wm * 16384;
        const char* Bh = Xt + 32768 + (wn >> 1) * 16384;
        i32x8 A8[4]; i32x8 B01[2], B23[2];

        // ---- q1: read A[0-3]+B[0-1] (12 x b128); stage A1(u+1)->Y; 8 MFMA
        #pragma unroll
        for (int mi = 0; mi < 4; ++mi) {
            i32x4 lo = *(const i32x4*)(Ah + aRow[mi] + ck0);
            i32x4 hi = *(const i32x4*)(Ah + aRow[mi] + ck1);
            A8[mi] = __builtin_shufflevector(lo, hi, 0, 1, 2, 3, 4, 5, 6, 7);
        }
        #pragma unroll
        for (int ni = 0; ni < 2; ++ni) {
            i32x4 lo = *(const i32x4*)(Bh + bRow[ni] + ck0);
            i32x4 hi = *(const i32x4*)(Bh + bRow[ni] + ck1);
            B01[ni] = __builtin_shufflevector(lo, hi, 0, 1, 2, 3, 4, 5, 6, 7);
        }
        if (u + 1 < KT2) stA(u + 1, 1, Y);
        __builtin_amdgcn_s_barrier();
        asm volatile("s_waitcnt lgkmcnt(0)" ::: "memory");
        __builtin_amdgcn_sched_barrier(0);
        __builtin_amdgcn_s_setprio(1);
        #pragma unroll
        for (int mi = 0; mi < 4; ++mi)
            #pragma unroll
            for (int ni = 0; ni < 2; ++ni)
                acc[mi][ni] = MFMA8(A8[mi], B01[ni], acc[mi][ni]);
        __builtin_amdgcn_s_setprio(0);
        __builtin_amdgcn_s_barrier();

        // ---- q2: read B[2-3] (4); 8 MFMA
        #pragma unroll
        for (int ni = 0; ni < 2; ++ni) {
            i32x4 lo = *(const i32x4*)(Bh + bRow[2 + ni] + ck0);
            i32x4 hi = *(const i32x4*)(Bh + bRow[2 + ni] + ck1);
            B23[ni] = __builtin_shufflevector(lo, hi, 0, 1, 2, 3, 4, 5, 6, 7);
        }
        __builtin_amdgcn_s_barrier();
        asm volatile("s_waitcnt lgkmcnt(0)" ::: "memory");
        __builtin_amdgcn_sched_barrier(0);
        __builtin_amdgcn_s_setprio(1);
        #pragma unroll
        for (int mi = 0; mi < 4; ++mi)
            #pragma unroll
            for (int ni = 0; ni < 2; ++ni)
                acc[mi][2 + ni] = MFMA8(A8[mi], B23[ni], acc[mi][2 + ni]);
        __builtin_amdgcn_s_setprio(0);
        __builtin_amdgcn_s_barrier();

        // ---- q3: read A[4-7] (8); stage B0(u+2)->X; 8 MFMA with B01
        #pragma unroll
        for (int mi = 0; mi < 4; ++mi) {
            i32x4 lo = *(const i32x4*)(Ah + aRow[4 + mi] + ck0);
            i32x4 hi = *(const i32x4*)(Ah + aRow[4 + mi] + ck1);
            A8[mi] = __builtin_shufflevector(lo, hi, 0, 1, 2, 3, 4, 5, 6, 7);
        }
        if (u + 2 < KT2) stB(u + 2, 0, Xw);
        __builtin_amdgcn_s_barrier();
        asm volatile("s_waitcnt lgkmcnt(0)" ::: "memory");
        __builtin_amdgcn_sched_barrier(0);
        __builtin_amdgcn_s_setprio(1);
        #pragma unroll
        for (int mi = 0; mi < 4; ++mi)
            #pragma unroll
            for (int ni = 0; ni < 2; ++ni)
                acc[4 + mi][ni] = MFMA8(A8[mi], B01[ni], acc[4 + mi][ni]);
        __builtin_amdgcn_s_setprio(0);
        __builtin_amdgcn_s_barrier();

        // ---- q4: stage A0(u+2)+B1(u+2)->X; pure 8 MFMA; vmcnt(6); bar
        if (u + 2 < KT2) { stA(u + 2, 0, Xw); stB(u + 2, 1, Xw); }
        __builtin_amdgcn_s_setprio(1);
        #pragma unroll
        for (int mi = 0; mi < 4; ++mi)
            #pragma unroll
            for (int ni = 0; ni < 2; ++ni)
                acc[4 + mi][2 + ni] = MFMA8(A8[mi], B23[ni], acc[4 + mi][2 + ni]);
        __builtin_amdgcn_s_setprio(0);
        if (u < KT2 - 2) { asm volatile("s_waitcnt vmcnt(6)" ::: "memory"); }
        else             { asm volatile("s_waitcnt vmcnt(0)" ::: "memory"); }
        __builtin_amdgcn_s_barrier();
    }

    // epilogue: raw partial store (bias/pos added in combine)
    #pragma unroll
    for (int mi = 0; mi < 8; ++mi) {
        #pragma unroll
        for (int ni = 0; ni < 4; ++ni) {
            int h = n0 + wn * 64 + ni * 16 + rl;
            #pragma unroll
            for (int r = 0; r < 4; ++r) {
                int l = wm * 128 + mi * 16 + g * 4 + r;
                if (l < L_) {
                    size_t o = ((size_t)b * L_ + l) * H_ + h;
                    if (kh == 0) outX[o] = acc[mi][ni][r];
                    else         P1[o]  = __float2bfloat16(acc[mi][ni][r]);
                }
            }
        }
    }
}

// ---------------- combine: out = p0(out) + p1 + b_proj + pos_table[ts] ----
__global__ __launch_bounds__(256) void combine(
    const __hip_bfloat16* __restrict__ P1,
    const float* __restrict__ bProj,
    const float* __restrict__ posTab,
    const int* __restrict__ tsIn,
    float* __restrict__ outX) {
    const int l = blockIdx.x, b = blockIdx.y;
    const int h = threadIdx.x * 4;
    const size_t o4 = ((size_t)(b * L_ + l) * H_ + h) >> 2;
    const int tsv = tsIn[b * T_ + l];
    float4 v = reinterpret_cast<float4*>(outX)[o4];
    ushort4 u = reinterpret_cast<const ushort4*>(P1)[o4];
    union { unsigned ui; float f; } c0, c1, c2, c3;
    c0.ui = (unsigned)u.x << 16; c1.ui = (unsigned)u.y << 16;
    c2.ui = (unsigned)u.z << 16; c3.ui = (unsigned)u.w << 16;
    float4 bp = reinterpret_cast<const float4*>(bProj)[h >> 2];
    float4 pt = reinterpret_cast<const float4*>(posTab + (size_t)tsv * H_)[h >> 2];
    v.x += c0.f + bp.x + pt.x;
    v.y += c1.f + bp.y + pt.y;
    v.z += c2.f + bp.z + pt.z;
    v.w += c3.f + bp.w + pt.w;
    reinterpret_cast<float4*>(outX)[o4] = v;
}

extern "C" void kernel_launch(void* const* d_in, const int* in_sizes, int n_in,
                              void* d_out, int out_size, void* d_ws, size_t ws_size,
                              hipStream_t stream) {
    (void)in_sizes; (void)n_in; (void)out_size; (void)ws_size;
    const float* spikes  = (const float*)d_in[0];
    const int*   smask   = (const int*)d_in[1];
    const int*   sts     = (const int*)d_in[2];
    const int*   dateIdx = (const int*)d_in[3];
    const float* Wemb    = (const float*)d_in[4];
    const float* bEmb    = (const float*)d_in[5];
    const float* Wproj   = (const float*)d_in[6];
    const float* bProj   = (const float*)d_in[7];
    const float* posTab  = (const float*)d_in[8];
    float* out = (float*)d_out;

    // workspace layout (bytes):
    // X18 fp8   [B][T][D]  : 25165824                 @ 0
    // SpB bf16  [B][T][C]  : 12582912                 @ 25165824
    // WeB bf16  [ND][D][C] : 18874368                 @ 37748736 (dead after gemm1)
    //   P1 bf16 [B][L][H]  : 16711680                 @ 37748736 (aliases WeB)
    // Wp8 fp8   [H][KP]    : 6291456                  @ 56623104
    char* ws = (char*)d_ws;
    unsigned char*  X18 = (unsigned char*)(ws);
    __hip_bfloat16* SpB = (__hip_bfloat16*)(ws + 25165824);
    __hip_bfloat16* WeB = (__hip_bfloat16*)(ws + 37748736);
    __hip_bfloat16* P1  = (__hip_bfloat16*)(ws + 37748736);
    unsigned char*  Wp8 = (unsigned char*)(ws + 56623104);

    hipFuncSetAttribute((const void*)gemm1_embed,
                        hipFuncAttributeMaxDynamicSharedMemorySize, 3 * BUFB);
    hipFuncSetAttribute((const void*)gemm2_proj,
                        hipFuncAttributeMaxDynamicSharedMemorySize, LDS2);

    prep<<<21536, 256, 0, stream>>>(spikes, Wemb, Wproj, smask, sts,
                                    SpB, WeB, Wp8, out);

    gemm1_embed<<<768, 512, 3 * BUFB, stream>>>(SpB, WeB, bEmb, dateIdx, X18);

    gemm2_proj<<<256, 512, LDS2, stream>>>(X18, Wp8, out, P1);

    dim3 gc(L_, B_);
    combine<<<gc, 256, 0, stream>>>(P1, bProj, posTab, sts, out);
}

// Round 13
// 133.617 us; speedup vs baseline: 1.5691x; 1.1143x over previous
//
#include <hip/hip_runtime.h>
#include <hip/hip_bf16.h>

// Problem constants
#define B_    32
#define T_    512
#define C_    384
#define D_    1536      // C*MULT
#define H_    1024
#define L_    255       // (T-SIZE)/STRIDE + 1
#define KP_   6144      // SIZE*D
#define ND_   16

// gemm1 (bf16, r3 engine): BM=256 BN=128 BK=64, 8 waves, tri-buffer 3x48KB,
//   counted vmcnt(12); epilogue writes X1 as fp8 e4m3.
// gemm2 (MX-fp8 K=128): BM=128(l) BN=128(h) BK=128, 4 waves (2x2), wave tile
//   64x64, double-buffered 2x32KB = 64KB LDS -> 2 blocks/CU (cross-block
//   overlap hides the barrier convoy). No split-K; epilogue fuses
//   b_proj + pos_table. Grid 512 XCD batch-major. vmcnt(8) counted.
#define BUFB 49152
#define G2BUF 32768

using f32x4 = __attribute__((ext_vector_type(4))) float;
using s16x8 = __attribute__((ext_vector_type(8))) short;
using i32x4 = __attribute__((ext_vector_type(4))) int;
using i32x8 = __attribute__((ext_vector_type(8))) int;

__device__ __forceinline__ void gld_lds16(const void* g, void* l) {
    __builtin_amdgcn_global_load_lds(
        (const __attribute__((address_space(1))) void*)g,
        (__attribute__((address_space(3))) void*)l,
        16, 0, 0);
}

__device__ __forceinline__ f32x4 MFMA(s16x8 a, s16x8 b, f32x4 c) {
    return __builtin_amdgcn_mfma_f32_16x16x32_bf16(a, b, c, 0, 0, 0);
}

// MX-fp8 K=128: A scale 1.0 (e8m0 0x7F), B scale 2^-4 (0x7B; Wp pre-scaled x16)
__device__ __forceinline__ f32x4 MFMA8(i32x8 a, i32x8 b, f32x4 c) {
    return __builtin_amdgcn_mfma_scale_f32_16x16x128_f8f6f4(
        a, b, c, 0, 0, 0, 0x7F7F7F7F, 0, 0x7B7B7B7B);
}

// ------------- prep: conversions + mask/ts, one launch ------------------
__global__ __launch_bounds__(256) void prep(
    const float* __restrict__ sp, const float* __restrict__ we,
    const float* __restrict__ wp, const int* __restrict__ mIn,
    const int* __restrict__ tIn,
    __hip_bfloat16* __restrict__ spB, __hip_bfloat16* __restrict__ weB,
    unsigned char* __restrict__ wp8, float* __restrict__ out) {
    int id = blockIdx.x * 256 + threadIdx.x;
    if (id < 3932160) {
        const float* src; __hip_bfloat16* dst; int idx;
        if (id < 1572864) { src = sp; dst = spB; idx = id; }
        else              { src = we; dst = weB; idx = id - 1572864; }
        float4 v = reinterpret_cast<const float4*>(src)[idx];
        __hip_bfloat16 o[4] = {__float2bfloat16(v.x), __float2bfloat16(v.y),
                               __float2bfloat16(v.z), __float2bfloat16(v.w)};
        reinterpret_cast<ushort4*>(dst)[idx] = *reinterpret_cast<ushort4*>(o);
    } else if (id < 5505024) {
        int idx = id - 3932160;
        float4 v = reinterpret_cast<const float4*>(wp)[idx];
        int w = __builtin_amdgcn_cvt_pk_fp8_f32(v.x * 16.f, v.y * 16.f, 0, false);
        w = __builtin_amdgcn_cvt_pk_fp8_f32(v.z * 16.f, v.w * 16.f, w, true);
        reinterpret_cast<int*>(wp8)[idx] = w;
    } else {
        int i = id - 5505024;
        if (i < B_ * L_) {
            int b = i / L_, l = i % L_;
            const int* mb = mIn + b * T_ + 2 * l;
            int m = mb[0] * mb[1] * mb[2] * mb[3];
            const size_t offM = (size_t)B_ * L_ * H_;
            out[offM + i] = (float)m;
            out[offM + (size_t)B_ * L_ + i] = (float)tIn[b * T_ + l];
        }
    }
}

// ======================= gemm1 engine (r3/r9, bf16) ======================
__device__ __forceinline__ void tile_compute(const char* la, const char* lb,
                                             f32x4 (&acc)[4][4],
                                             int rA, int rB, int g) {
    const int sxA = rA & 7, sxB = rB & 7;
    s16x8 af0[4], bf0[4], af1[4], bf1[4];
    #pragma unroll
    for (int mi = 0; mi < 4; ++mi)
        af0[mi] = *(const s16x8*)(la + rA * 128 + mi * 2048 + ((g ^ sxA) << 4));
    #pragma unroll
    for (int ni = 0; ni < 4; ++ni)
        bf0[ni] = *(const s16x8*)(lb + rB * 128 + ni * 2048 + ((g ^ sxB) << 4));
    #pragma unroll
    for (int mi = 0; mi < 4; ++mi)
        af1[mi] = *(const s16x8*)(la + rA * 128 + mi * 2048 + (((4 + g) ^ sxA) << 4));
    #pragma unroll
    for (int ni = 0; ni < 4; ++ni)
        bf1[ni] = *(const s16x8*)(lb + rB * 128 + ni * 2048 + (((4 + g) ^ sxB) << 4));
    asm volatile("s_waitcnt lgkmcnt(8)" ::: "memory");
    __builtin_amdgcn_sched_barrier(0);
    __builtin_amdgcn_s_setprio(1);
    #pragma unroll
    for (int mi = 0; mi < 4; ++mi)
        #pragma unroll
        for (int ni = 0; ni < 4; ++ni)
            acc[mi][ni] = MFMA(af0[mi], bf0[ni], acc[mi][ni]);
    __builtin_amdgcn_s_setprio(0);
    asm volatile("s_waitcnt lgkmcnt(0)" ::: "memory");
    __builtin_amdgcn_sched_barrier(0);
    __builtin_amdgcn_s_setprio(1);
    #pragma unroll
    for (int mi = 0; mi < 4; ++mi)
        #pragma unroll
        for (int ni = 0; ni < 4; ++ni)
            acc[mi][ni] = MFMA(af1[mi], bf1[ni], acc[mi][ni]);
    __builtin_amdgcn_s_setprio(0);
}

__global__ __launch_bounds__(512, 2) void gemm1_embed(
    const __hip_bfloat16* __restrict__ Sp,
    const __hip_bfloat16* __restrict__ We,
    const float* __restrict__ bEmb,
    const int* __restrict__ dateIdx,
    unsigned char* __restrict__ X18) {
    extern __shared__ __align__(16) char lds[];
    const int tid  = threadIdx.x;
    const int lane = tid & 63, wid = tid >> 6;
    const int wr = wid >> 1, wc = wid & 1;
    const int id   = blockIdx.x;             // 0..767
    const int xcd  = id & 7, slot = id >> 3; // slot 0..95
    const int b    = xcd * 4 + slot / 24;
    const int tile = slot % 24;
    const int m0   = (tile % 2) * 256;
    const int n0   = (tile / 2) * 128;
    const int didx = dateIdx[b];
    const __hip_bfloat16* A  = Sp + (size_t)b * T_ * C_;
    const __hip_bfloat16* Bm = We + (size_t)didx * D_ * C_;
    const int KT = C_ / 64;              // 6

    auto stage = [&](int kt, int buf) {
        char* lA = lds + buf * BUFB;
        char* lB = lA + 32768;
        int k0 = kt * 64;
        #pragma unroll
        for (int i = 0; i < 4; ++i) {
            int p = i * 512 + tid;
            int row = p >> 3;
            int clog = (p & 7) ^ (row & 7);
            gld_lds16(A + (size_t)(m0 + row) * C_ + k0 + clog * 8,
                      lA + (i * 512 + wid * 64) * 16);
        }
        #pragma unroll
        for (int i = 0; i < 2; ++i) {
            int p = i * 512 + tid;
            int row = p >> 3;
            int clog = (p & 7) ^ (row & 7);
            gld_lds16(Bm + (size_t)(n0 + row) * C_ + k0 + clog * 8,
                      lB + (i * 512 + wid * 64) * 16);
        }
    };

    f32x4 acc[4][4] = {};
    const int rl = lane & 15, g = lane >> 4;
    const int rA = wr * 64 + rl, rB = wc * 64 + rl;

    stage(0, 0);
    stage(1, 1);
    for (int kt = 0; kt < KT - 2; ++kt) {
        stage(kt + 2, (kt + 2) % 3);
        asm volatile("s_waitcnt vmcnt(12)" ::: "memory");
        __builtin_amdgcn_s_barrier();
        const char* la = lds + (kt % 3) * BUFB;
        tile_compute(la, la + 32768, acc, rA, rB, g);
        __builtin_amdgcn_s_barrier();
    }
    asm volatile("s_waitcnt vmcnt(6)" ::: "memory");
    __builtin_amdgcn_s_barrier();
    {
        const char* la = lds + ((KT - 2) % 3) * BUFB;
        tile_compute(la, la + 32768, acc, rA, rB, g);
    }
    asm volatile("s_waitcnt vmcnt(0)" ::: "memory");
    __builtin_amdgcn_s_barrier();
    {
        const char* la = lds + ((KT - 1) % 3) * BUFB;
        tile_compute(la, la + 32768, acc, rA, rB, g);
    }

    // epilogue: + bias, exact gelu, * 32, store fp8 e4m3
    #pragma unroll
    for (int mi = 0; mi < 4; ++mi) {
        #pragma unroll
        for (int ni = 0; ni < 4; ++ni) {
            int col = n0 + wc * 64 + ni * 16 + rl;              // d
            float bg = bEmb[didx * D_ + col];
            #pragma unroll
            for (int r = 0; r < 4; ++r) {
                int row = m0 + wr * 64 + mi * 16 + g * 4 + r;   // t
                float v = acc[mi][ni][r] + bg;
                float gl = 0.5f * v * (1.0f + erff(v * 0.70710678118f)) * 32.0f;
                int pk = __builtin_amdgcn_cvt_pk_fp8_f32(gl, gl, 0, false);
                X18[((size_t)b * T_ + row) * D_ + col] = (unsigned char)pk;
            }
        }
    }
}

// ============ gemm2: MX-fp8 K128, 2 blocks/CU, no split-K ================
// grid 512: xcd=id&7; slot=id>>3 (0..63); b=xcd*4+(slot>>4);
// t=slot&15: m0=(t&1)*128, n0=(t>>1)*128. 48 K128-tiles, s-inner order.
__global__ __launch_bounds__(256, 2) void gemm2_proj(
    const unsigned char* __restrict__ X18,     // [B][T][D] fp8
    const unsigned char* __restrict__ Wp8,     // [H][KP] fp8 (x16 scaled)
    const float* __restrict__ bProj,
    const float* __restrict__ posTab,          // [MAXF][H] f32
    const int* __restrict__ tsIn,              // [B][T]
    float* __restrict__ outX) {                // [B][L][H]
    extern __shared__ __align__(16) char lds[];
    const int tid  = threadIdx.x;
    const int lane = tid & 63, wid = tid >> 6;
    const int wm = wid >> 1, wn = wid & 1;
    const int id   = blockIdx.x;               // 0..511
    const int xcd  = id & 7, slot = id >> 3;   // 0..63
    const int b    = xcd * 4 + (slot >> 4);
    const int t    = slot & 15;
    const int m0   = (t & 1) * 128;            // l base
    const int n0   = (t >> 1) * 128;           // h base
    const unsigned char* Xb = X18 + (size_t)b * T_ * D_;
    const int KT = 48;                         // K128 tiles

    // staging: A tile [128 l-rows][128 fp8] 16KB + B tile 16KB per buffer.
    // chunk id p (0..1023 per operand), row=p>>3, phys chunk c = (p&7)^(row&7).
    const unsigned char* aP[4]; const unsigned char* bP[4]; int dstC[4];
    #pragma unroll
    for (int i = 0; i < 4; ++i) {
        int p = i * 256 + tid;
        int row = p >> 3;
        int c = (p & 7) ^ (row & 7);
        int l = m0 + row; if (l > 254) l = 254;
        aP[i] = Xb + (size_t)(2 * l) * D_ + c * 16;
        bP[i] = Wp8 + (size_t)(n0 + row) * KP_ + c * 16;
        dstC[i] = (i * 256 + wid * 64) * 16;
    }
    auto stage = [&](int kt, char* buf) {
        int ko = (kt & 3) * D_ + (kt >> 2) * 128;   // s-inner K order
        #pragma unroll
        for (int i = 0; i < 4; ++i) {
            gld_lds16(aP[i] + ko, buf + dstC[i]);
            gld_lds16(bP[i] + ko, buf + 16384 + dstC[i]);
        }
    };

    // fragment geometry: lane reads 32B of its row (chunks 2g, 2g+1 logical)
    const int rl = lane & 15, g = lane >> 4, sx = rl & 7;
    const int ck0 = ((2 * g) ^ sx) << 4;
    const int ck1 = ((2 * g + 1) ^ sx) << 4;
    int aOff[4], bOff[4];
    #pragma unroll
    for (int mi = 0; mi < 4; ++mi) aOff[mi] = (wm * 64 + mi * 16 + rl) * 128;
    #pragma unroll
    for (int ni = 0; ni < 4; ++ni) bOff[ni] = 16384 + (wn * 64 + ni * 16 + rl) * 128;

    union u8x32 { i32x8 v; i32x4 h[2]; };
    f32x4 acc[4][4] = {};

    stage(0, lds);
    for (int u = 0; u < KT; ++u) {
        char* cur = lds + (u & 1) * G2BUF;
        if (u + 1 < KT) stage(u + 1, lds + ((u + 1) & 1) * G2BUF);
        if (u + 1 < KT) { asm volatile("s_waitcnt vmcnt(8)" ::: "memory"); }
        else            { asm volatile("s_waitcnt vmcnt(0)" ::: "memory"); }
        __builtin_amdgcn_s_barrier();

        u8x32 A[4], Bv[4];
        #pragma unroll
        for (int mi = 0; mi < 4; ++mi) {
            A[mi].h[0] = *(const i32x4*)(cur + aOff[mi] + ck0);
            A[mi].h[1] = *(const i32x4*)(cur + aOff[mi] + ck1);
        }
        #pragma unroll
        for (int ni = 0; ni < 4; ++ni) {
            Bv[ni].h[0] = *(const i32x4*)(cur + bOff[ni] + ck0);
            Bv[ni].h[1] = *(const i32x4*)(cur + bOff[ni] + ck1);
        }
        #pragma unroll
        for (int ni = 0; ni < 4; ++ni)
            #pragma unroll
            for (int mi = 0; mi < 4; ++mi)
                acc[mi][ni] = MFMA8(A[mi].v, Bv[ni].v, acc[mi][ni]);
        __builtin_amdgcn_s_barrier();
    }

    // epilogue: + b_proj + pos_table[ts[l]], fp32 store
    #pragma unroll
    for (int mi = 0; mi < 4; ++mi) {
        #pragma unroll
        for (int ni = 0; ni < 4; ++ni) {
            int h = n0 + wn * 64 + ni * 16 + rl;
            float bp = bProj[h];
            #pragma unroll
            for (int r = 0; r < 4; ++r) {
                int l = m0 + wm * 64 + mi * 16 + g * 4 + r;
                if (l < L_) {
                    int tsv = tsIn[b * T_ + l];
                    float v = acc[mi][ni][r] + bp + posTab[(size_t)tsv * H_ + h];
                    outX[((size_t)b * L_ + l) * H_ + h] = v;
                }
            }
        }
    }
}

extern "C" void kernel_launch(void* const* d_in, const int* in_sizes, int n_in,
                              void* d_out, int out_size, void* d_ws, size_t ws_size,
                              hipStream_t stream) {
    (void)in_sizes; (void)n_in; (void)out_size; (void)ws_size;
    const float* spikes  = (const float*)d_in[0];
    const int*   smask   = (const int*)d_in[1];
    const int*   sts     = (const int*)d_in[2];
    const int*   dateIdx = (const int*)d_in[3];
    const float* Wemb    = (const float*)d_in[4];
    const float* bEmb    = (const float*)d_in[5];
    const float* Wproj   = (const float*)d_in[6];
    const float* bProj   = (const float*)d_in[7];
    const float* posTab  = (const float*)d_in[8];
    float* out = (float*)d_out;

    // workspace layout (bytes):
    // X18 fp8   [B][T][D]  : 25165824   @ 0
    // SpB bf16  [B][T][C]  : 12582912   @ 25165824
    // WeB bf16  [ND][D][C] : 18874368   @ 37748736
    // Wp8 fp8   [H][KP]    : 6291456    @ 56623104
    char* ws = (char*)d_ws;
    unsigned char*  X18 = (unsigned char*)(ws);
    __hip_bfloat16* SpB = (__hip_bfloat16*)(ws + 25165824);
    __hip_bfloat16* WeB = (__hip_bfloat16*)(ws + 37748736);
    unsigned char*  Wp8 = (unsigned char*)(ws + 56623104);

    hipFuncSetAttribute((const void*)gemm1_embed,
                        hipFuncAttributeMaxDynamicSharedMemorySize, 3 * BUFB);
    hipFuncSetAttribute((const void*)gemm2_proj,
                        hipFuncAttributeMaxDynamicSharedMemorySize, 2 * G2BUF);

    prep<<<21536, 256, 0, stream>>>(spikes, Wemb, Wproj, smask, sts,
                                    SpB, WeB, Wp8, out);

    gemm1_embed<<<768, 512, 3 * BUFB, stream>>>(SpB, WeB, bEmb, dateIdx, X18);

    gemm2_proj<<<512, 256, 2 * G2BUF, stream>>>(X18, Wp8, bProj, posTab, sts, out);
}